// Round 1
// baseline (5709.719 us; speedup 1.0000x reference)
//
#include <hip/hip_runtime.h>

// ---------------- constants ----------------
static constexpr int kL = 12;
static constexpr int kD = 384;
static constexpr int kH = 6;
static constexpr int kHD = 64;
static constexpr int kB = 64;
static constexpr int kNP = 196;      // patches
static constexpr int kBAND = 197;    // tokens incl cls (max)
static constexpr int kNCLS = 1000;
static constexpr float kSCALE = 0.125f;   // 64^-0.5
static constexpr float kEPS = 1e-6f;

// ---------------- small utils ----------------
__device__ __forceinline__ float gelu_f(float x) {
    return 0.5f * x * (1.0f + erff(x * 0.70710678118654752440f));
}

// ---------------- state init ----------------
__global__ __launch_bounds__(64) void k_init(int* si, float* sf) {
    if (threadIdx.x == 0) { si[0] = kBAND; si[1] = kBAND; sf[0] = 1.0f; }
}

__global__ __launch_bounds__(64) void k_commit(int* si) {
    if (threadIdx.x == 0) si[0] = si[1];
}

// ---------------- im2col for patch embed ----------------
__global__ __launch_bounds__(256) void k_im2col(const float* __restrict__ x, float* __restrict__ A) {
    int pt = blockIdx.x;              // b*196 + t
    int b = pt / kNP, t = pt - b * kNP;
    int py = t / 14, px = t - py * 14;
    const float* xb = x + (size_t)b * 3 * 224 * 224;
    float* arow = A + (size_t)pt * 768;
    for (int k = threadIdx.x; k < 768; k += 256) {
        int c = k >> 8;
        int r = k & 255;
        int ky = r >> 4, kx = r & 15;
        arow[k] = xb[((size_t)c * 224 + py * 16 + ky) * 224 + px * 16 + kx];
    }
}

// ---------------- assemble xt = [cls; patches] + pos ----------------
__global__ __launch_bounds__(384) void k_assemble(const float* __restrict__ xp,
                                                  const float* __restrict__ patch_b,
                                                  const float* __restrict__ cls,
                                                  const float* __restrict__ pos,
                                                  float* __restrict__ xt) {
    int t = blockIdx.x % kBAND, b = blockIdx.x / kBAND;
    int c = threadIdx.x;
    float v;
    if (t == 0) v = cls[c] + pos[c];
    else v = xp[((size_t)(b * kNP + t - 1)) * kD + c] + patch_b[c] + pos[(size_t)t * kD + c];
    xt[((size_t)b * kBAND + t) * kD + c] = v;
}

// ---------------- generic fp32 GEMM: C[row][n] = act(A[row]·W[n] + bias[n]) (+R) ----------------
// A rows are (b, t) bands of `band` tokens; row valid iff t < Nt.
__global__ __launch_bounds__(256) void k_gemm(
    const float* __restrict__ A, int lda,
    const float* __restrict__ W,
    const float* __restrict__ bias,
    float* __restrict__ C, int ldc,
    const float* __restrict__ R,
    int K, int band, const int* NtPtr, int ntConst, int act, int gate)
{
    __shared__ __align__(16) float As[16][68];
    __shared__ __align__(16) float Ws[16][68];
    int Nt = NtPtr ? NtPtr[0] : ntConst;
    if (gate && (Nt - 1) <= 16) return;   // decision path disabled
    int r0 = blockIdx.x * 64;
    int n0 = blockIdx.y * 64;
    int t0 = r0 % band;
    if (!(t0 < Nt || t0 + 63 >= band)) return;

    int tid = threadIdx.x;
    int lrow = tid >> 2;
    int lk = (tid & 3) << 2;
    int grow = r0 + lrow;
    int gb = grow / band;
    int gt = grow - gb * band;
    bool avalid = (gt < Nt);
    const float* aP = A + (size_t)grow * lda + lk;
    const float* wP = W + (size_t)(n0 + lrow) * K + lk;

    int tx = tid & 15, ty = tid >> 4;
    float acc[4][4];
#pragma unroll
    for (int i = 0; i < 4; i++)
#pragma unroll
        for (int j = 0; j < 4; j++) acc[i][j] = 0.f;

    for (int k0 = 0; k0 < K; k0 += 16) {
        float4 av = avalid ? *(const float4*)(aP + k0) : make_float4(0.f, 0.f, 0.f, 0.f);
        float4 wv = *(const float4*)(wP + k0);
        As[lk + 0][lrow] = av.x; As[lk + 1][lrow] = av.y; As[lk + 2][lrow] = av.z; As[lk + 3][lrow] = av.w;
        Ws[lk + 0][lrow] = wv.x; Ws[lk + 1][lrow] = wv.y; Ws[lk + 2][lrow] = wv.z; Ws[lk + 3][lrow] = wv.w;
        __syncthreads();
#pragma unroll
        for (int kk = 0; kk < 16; kk++) {
            float4 a4 = *(const float4*)&As[kk][ty << 2];
            float4 w4 = *(const float4*)&Ws[kk][tx << 2];
            float aa[4] = { a4.x, a4.y, a4.z, a4.w };
            float ww[4] = { w4.x, w4.y, w4.z, w4.w };
#pragma unroll
            for (int i = 0; i < 4; i++)
#pragma unroll
                for (int j = 0; j < 4; j++) acc[i][j] += aa[i] * ww[j];
        }
        __syncthreads();
    }

    float4 bv = bias ? *(const float4*)(bias + n0 + (tx << 2)) : make_float4(0.f, 0.f, 0.f, 0.f);
#pragma unroll
    for (int i = 0; i < 4; i++) {
        int row = r0 + (ty << 2) + i;
        int b_ = row / band, t_ = row - b_ * band;
        if (t_ >= Nt) continue;
        float4 o;
        o.x = acc[i][0] + bv.x; o.y = acc[i][1] + bv.y; o.z = acc[i][2] + bv.z; o.w = acc[i][3] + bv.w;
        if (act == 1) { o.x = gelu_f(o.x); o.y = gelu_f(o.y); o.z = gelu_f(o.z); o.w = gelu_f(o.w); }
        if (R) {
            float4 r4 = *(const float4*)(R + (size_t)row * ldc + n0 + (tx << 2));
            o.x += r4.x; o.y += r4.y; o.z += r4.z; o.w += r4.w;
        }
        *(float4*)(C + (size_t)row * ldc + n0 + (tx << 2)) = o;
    }
}

// ---------------- LayerNorm over D=384 ----------------
__global__ __launch_bounds__(384) void k_ln(const float* __restrict__ X, float* __restrict__ Y,
                                            const float* __restrict__ w, const float* __restrict__ b,
                                            const int* NtPtr, int gate) {
    int Nt = NtPtr[0];
    if (gate && (Nt - 1) <= 16) return;
    int t = blockIdx.x % kBAND, bb = blockIdx.x / kBAND;
    if (t >= Nt) return;
    int tid = threadIdx.x;
    const float* row = X + ((size_t)bb * kBAND + t) * kD;
    float v = row[tid];
    float s1 = v, s2 = v * v;
#pragma unroll
    for (int off = 32; off; off >>= 1) { s1 += __shfl_down(s1, off, 64); s2 += __shfl_down(s2, off, 64); }
    __shared__ float r1[8], r2[8];
    int wid = tid >> 6, lane = tid & 63;
    if (lane == 0) { r1[wid] = s1; r2[wid] = s2; }
    __syncthreads();
    float sum = r1[0] + r1[1] + r1[2] + r1[3] + r1[4] + r1[5];
    float sq = r2[0] + r2[1] + r2[2] + r2[3] + r2[4] + r2[5];
    float mu = sum * (1.f / 384.f);
    float var = sq * (1.f / 384.f) - mu * mu;
    var = fmaxf(var, 0.f);
    Y[((size_t)bb * kBAND + t) * kD + tid] = (v - mu) * rsqrtf(var + kEPS) * w[tid] + b[tid];
}

// ---------------- LN of cls token only (final norm) ----------------
__global__ __launch_bounds__(384) void k_lncls(const float* __restrict__ X,
                                               const float* __restrict__ w, const float* __restrict__ b,
                                               float* __restrict__ Y) {
    int bb = blockIdx.x;
    int tid = threadIdx.x;
    const float* row = X + (size_t)bb * kBAND * kD;
    float v = row[tid];
    float s1 = v, s2 = v * v;
#pragma unroll
    for (int off = 32; off; off >>= 1) { s1 += __shfl_down(s1, off, 64); s2 += __shfl_down(s2, off, 64); }
    __shared__ float r1[8], r2[8];
    int wid = tid >> 6, lane = tid & 63;
    if (lane == 0) { r1[wid] = s1; r2[wid] = s2; }
    __syncthreads();
    float sum = r1[0] + r1[1] + r1[2] + r1[3] + r1[4] + r1[5];
    float sq = r2[0] + r2[1] + r2[2] + r2[3] + r2[4] + r2[5];
    float mu = sum * (1.f / 384.f);
    float var = fmaxf(sq * (1.f / 384.f) - mu * mu, 0.f);
    Y[(size_t)bb * kD + tid] = (v - mu) * rsqrtf(var + kEPS) * w[tid] + b[tid];
}

// ---------------- fused attention: one wave per (b,h,t) ----------------
__global__ __launch_bounds__(64) void k_attn(const float* __restrict__ qkv, float* __restrict__ o,
                                             const int* si) {
    int Nt = si[0];
    int t = blockIdx.x % kBAND;
    int bh = blockIdx.x / kBAND;
    int h = bh % kH, b = bh / kH;
    if (t >= Nt) return;
    int lane = threadIdx.x;
    const float* base = qkv + (size_t)b * kBAND * 1152;
    __shared__ float qs[64];
    __shared__ float as[256];
    qs[lane] = base[(size_t)t * 1152 + h * 64 + lane];
    __syncthreads();
    float sv[4];
    float m = -INFINITY;
#pragma unroll
    for (int i = 0; i < 4; i++) {
        int j = lane + (i << 6);
        float s = -INFINITY;
        if (j < Nt) {
            const float* krow = base + (size_t)j * 1152 + 384 + h * 64;
            float acc = 0.f;
#pragma unroll
            for (int d = 0; d < 64; d += 4) {
                float4 k4 = *(const float4*)(krow + d);
                acc += qs[d] * k4.x + qs[d + 1] * k4.y + qs[d + 2] * k4.z + qs[d + 3] * k4.w;
            }
            s = acc * kSCALE;
        }
        sv[i] = s;
        m = fmaxf(m, s);
    }
#pragma unroll
    for (int off = 32; off; off >>= 1) m = fmaxf(m, __shfl_xor(m, off, 64));
    float sum = 0.f;
#pragma unroll
    for (int i = 0; i < 4; i++) {
        int j = lane + (i << 6);
        float e = (j < Nt) ? expf(sv[i] - m) : 0.f;
        sv[i] = e; sum += e;
    }
#pragma unroll
    for (int off = 32; off; off >>= 1) sum += __shfl_xor(sum, off, 64);
    float inv = 1.f / sum;
#pragma unroll
    for (int i = 0; i < 4; i++) { int j = lane + (i << 6); as[j] = sv[i] * inv; }
    __syncthreads();
    float acc = 0.f;
    const float* vbase = base + 768 + h * 64 + lane;
    for (int j = 0; j < Nt; j++) acc += as[j] * vbase[(size_t)j * 1152];
    o[((size_t)b * kBAND + t) * kD + h * 64 + lane] = acc;
}

// ---------------- decision stage 1: a_cls * vnorm per (b,h,j) ----------------
__global__ __launch_bounds__(256) void k_dec1(const float* __restrict__ qkv, float* __restrict__ imph,
                                              const int* si) {
    int Nt = si[0];
    if (Nt - 1 <= 16) return;
    int h = blockIdx.x % kH, b = blockIdx.x / kH;
    const float* base = qkv + (size_t)b * kBAND * 1152;
    __shared__ float qs[64];
    __shared__ float red[256];
    int tid = threadIdx.x;
    if (tid < 64) qs[tid] = base[h * 64 + tid];   // q of cls (token 0)
    __syncthreads();
    int j = tid;
    float s = -INFINITY, vn = 0.f, e = 0.f;
    if (j < Nt) {
        const float* krow = base + (size_t)j * 1152 + 384 + h * 64;
        const float* vrow = base + (size_t)j * 1152 + 768 + h * 64;
        float acc = 0.f, v2 = 0.f;
#pragma unroll
        for (int d = 0; d < 64; d += 4) {
            float4 k4 = *(const float4*)(krow + d);
            float4 v4 = *(const float4*)(vrow + d);
            acc += qs[d] * k4.x + qs[d + 1] * k4.y + qs[d + 2] * k4.z + qs[d + 3] * k4.w;
            v2 += v4.x * v4.x + v4.y * v4.y + v4.z * v4.z + v4.w * v4.w;
        }
        s = acc * kSCALE;
        vn = sqrtf(v2);
    }
    red[tid] = s; __syncthreads();
    for (int st = 128; st; st >>= 1) { if (tid < st) red[tid] = fmaxf(red[tid], red[tid + st]); __syncthreads(); }
    float m = red[0]; __syncthreads();
    e = (j < Nt) ? expf(s - m) : 0.f;
    red[tid] = e; __syncthreads();
    for (int st = 128; st; st >>= 1) { if (tid < st) red[tid] += red[tid + st]; __syncthreads(); }
    float inv = 1.f / red[0];
    if (j < Nt) imph[((size_t)b * kH + h) * kBAND + j] = e * inv * vn;
}

// ---------------- decision stage 2: imp + per-batch sums ----------------
__global__ __launch_bounds__(256) void k_dec2(const float* __restrict__ imph, float* __restrict__ imp,
                                              float* __restrict__ sab, const int* si) {
    int Nt = si[0];
    if (Nt - 1 <= 16) return;
    int b = blockIdx.x;
    int tid = threadIdx.x;
    __shared__ float red[256];
    float v = 0.f;
    if (tid < Nt) {
        float s = 0.f;
#pragma unroll
        for (int h = 0; h < kH; h++) s += imph[((size_t)b * kH + h) * kBAND + tid];
        v = s * (1.f / 6.f);
        imp[(size_t)b * kBAND + tid] = v;
    }
    red[tid] = v; __syncthreads();
    for (int st = 128; st; st >>= 1) { if (tid < st) red[tid] += red[tid + st]; __syncthreads(); }
    if (tid == 0) {
        float sa = red[0];
        float sp = sa - imp[(size_t)b * kBAND];
        sab[2 * b] = sa; sab[2 * b + 1] = sp;
    }
}

// ---------------- decision stage 3: mass, ratio, top-k, keep_idx ----------------
__global__ __launch_bounds__(256) void k_dec3(int* si, float* sf, const float* __restrict__ imp,
                                              const float* __restrict__ sab, int* keep) {
    int Nt = si[0];
    int tid = threadIdx.x;
    bool active = (Nt - 1 > 16);
    if (!active) {
        for (int j = tid; j < Nt; j += 256) keep[j] = j;
        if (tid == 0) si[1] = Nt;
        return;
    }
    int N = Nt - 1;
    __shared__ float red[256];
    __shared__ int ri[256];
    __shared__ float sc[200];
    __shared__ int flag[200];
    float v = 0.f;
    if (tid < kB) v = sab[2 * tid + 1] / (sab[2 * tid] + kEPS);
    red[tid] = v; __syncthreads();
    for (int st = 128; st; st >>= 1) { if (tid < st) red[tid] += red[tid + st]; __syncthreads(); }
    float mass = red[0] * (1.f / 64.f);
    float prev = sf[0];
    float ratio = 0.5f * mass / (prev + kEPS);
    ratio = fminf(fmaxf(ratio, 0.f), 1.f);
    int N_next = (int)((double)N * (double)ratio);
    if (N_next < 16) N_next = 16;
    if (tid == 0) sf[0] = mass;     // prev_mass = mass (reference updates whenever decision runs)
    __syncthreads();
    if (N_next >= N) {
        for (int j = tid; j < Nt; j += 256) keep[j] = j;
        if (tid == 0) si[1] = Nt;
        return;
    }
    // scores[j] = mean_b imp[b][j+1]
    for (int j = tid; j < N; j += 256) {
        float s = 0.f;
        for (int b = 0; b < kB; b++) s += imp[(size_t)b * kBAND + j + 1];
        sc[j] = s * (1.f / 64.f);
        flag[j] = 0;
    }
    __syncthreads();
    // iterative argmax selection (ties -> smaller index, matches lax.top_k)
    for (int it = 0; it < N_next; ++it) {
        float mv = (tid < N) ? sc[tid] : -INFINITY;
        int mi = tid;
        red[tid] = mv; ri[tid] = mi; __syncthreads();
        for (int st = 128; st; st >>= 1) {
            if (tid < st) {
                float ov = red[tid + st]; int oi = ri[tid + st];
                if (ov > red[tid] || (ov == red[tid] && oi < ri[tid])) { red[tid] = ov; ri[tid] = oi; }
            }
            __syncthreads();
        }
        if (tid == 0) { flag[ri[0]] = 1; sc[ri[0]] = -INFINITY; }
        __syncthreads();
    }
    if (tid == 0) {
        keep[0] = 0;
        int pos = 1;
        for (int j = 0; j < N; j++) if (flag[j]) keep[pos++] = j + 1;
        si[1] = N_next + 1;
    }
}

// ---------------- gather tokens ----------------
__global__ __launch_bounds__(384) void k_gather(const float* __restrict__ src, float* __restrict__ dst,
                                                const int* keep, const int* si) {
    int NtNew = si[1];
    int t = blockIdx.x % kBAND, b = blockIdx.x / kBAND;
    if (t >= NtNew) return;
    int sj = keep[t];
    dst[((size_t)b * kBAND + t) * kD + threadIdx.x] = src[((size_t)b * kBAND + sj) * kD + threadIdx.x];
}

// ---------------- head ----------------
__global__ __launch_bounds__(256) void k_head(const float* __restrict__ xn, const float* __restrict__ hw,
                                              const float* __restrict__ hb, float* __restrict__ out) {
    int b = blockIdx.x >> 2;
    int n = ((blockIdx.x & 3) << 8) + threadIdx.x;
    __shared__ float xs[384];
    for (int i = threadIdx.x; i < 384; i += 256) xs[i] = xn[(size_t)b * kD + i];
    __syncthreads();
    if (n >= kNCLS) return;
    const float* wrow = hw + (size_t)n * kD;
    float acc = 0.f;
#pragma unroll 8
    for (int d = 0; d < kD; d += 4) {
        float4 w4 = *(const float4*)(wrow + d);
        acc += xs[d] * w4.x + xs[d + 1] * w4.y + xs[d + 2] * w4.z + xs[d + 3] * w4.w;
    }
    out[(size_t)b * kNCLS + n] = acc + hb[n];
}

// ---------------- host launch ----------------
extern "C" void kernel_launch(void* const* d_in, const int* in_sizes, int n_in,
                              void* d_out, int out_size, void* d_ws, size_t ws_size,
                              hipStream_t stream) {
    const float* x       = (const float*)d_in[0];
    const float* patch_w = (const float*)d_in[1];
    const float* patch_b = (const float*)d_in[2];
    const float* cls_tok = (const float*)d_in[3];
    const float* pos     = (const float*)d_in[4];
    const float* ln1w    = (const float*)d_in[5];
    const float* ln1b    = (const float*)d_in[6];
    const float* qkvw    = (const float*)d_in[7];
    const float* qkvb    = (const float*)d_in[8];
    const float* projw   = (const float*)d_in[9];
    const float* projb   = (const float*)d_in[10];
    const float* ln2w    = (const float*)d_in[11];
    const float* ln2b    = (const float*)d_in[12];
    const float* fc1w    = (const float*)d_in[13];
    const float* fc1b    = (const float*)d_in[14];
    const float* fc2w    = (const float*)d_in[15];
    const float* fc2b    = (const float*)d_in[16];
    const float* normw   = (const float*)d_in[17];
    const float* normb   = (const float*)d_in[18];
    const float* headw   = (const float*)d_in[19];
    const float* headb   = (const float*)d_in[20];
    float* out = (float*)d_out;

    char* ws = (char*)d_ws;
    const size_t MB = 1024ull * 1024ull;
    int*   si   = (int*)ws;
    float* sf   = (float*)(ws + 64);
    int*   keep = (int*)(ws + 256);
    float* imph = (float*)(ws + 4096);
    float* imp  = (float*)(ws + 512 * 1024);
    float* sab  = (float*)(ws + 640 * 1024);
    float* xnm  = (float*)(ws + 704 * 1024);
    float* xtA  = (float*)(ws + 1 * MB);
    float* xtB  = (float*)(ws + 21 * MB);
    float* xn   = (float*)(ws + 41 * MB);   // aliased: xp (patch out) and attention out
    float* qkv  = (float*)(ws + 61 * MB);
    float* hbuf = (float*)(ws + 121 * MB);  // aliased: im2col buffer
    float* Aim  = hbuf;
    float* xp   = xn;
    float* obuf = xn;

    k_init<<<1, 64, 0, stream>>>(si, sf);
    k_im2col<<<kB * kNP, 256, 0, stream>>>(x, Aim);
    // patch embed GEMM: M=12544, K=768, N=384 (all rows valid)
    k_gemm<<<dim3(kB * kNP / 64, kD / 64), 256, 0, stream>>>(
        Aim, 768, patch_w, (const float*)nullptr, xp, kD, (const float*)nullptr,
        768, kNP, (const int*)nullptr, kNP, 0, 0);
    k_assemble<<<kB * kBAND, 384, 0, stream>>>(xp, patch_b, cls_tok, pos, xtA);

    float* cur = xtA; float* oth = xtB;
    for (int l = 0; l < kL; ++l) {
        const float* l1w = ln1w + l * kD;  const float* l1b = ln1b + l * kD;
        const float* qw  = qkvw + (size_t)l * 1152 * kD; const float* qb = qkvb + l * 1152;
        const float* pw  = projw + (size_t)l * kD * kD;  const float* pb = projb + l * kD;
        const float* l2w = ln2w + l * kD;  const float* l2b = ln2b + l * kD;
        const float* f1w = fc1w + (size_t)l * 1536 * kD; const float* f1b = fc1b + l * 1536;
        const float* f2w = fc2w + (size_t)l * kD * 1536; const float* f2b = fc2b + l * kD;

        // ---- pruning decision (device-gated on Nt-1 > 16) ----
        k_ln<<<kB * kBAND, 384, 0, stream>>>(cur, xn, l1w, l1b, si, 1);
        k_gemm<<<dim3(197, 18), 256, 0, stream>>>(xn, kD, qw, qb, qkv, 1152, (const float*)nullptr,
                                                  kD, kBAND, si, 0, 0, 1);
        k_dec1<<<kB * kH, 256, 0, stream>>>(qkv, imph, si);
        k_dec2<<<kB, 256, 0, stream>>>(imph, imp, sab, si);
        k_dec3<<<1, 256, 0, stream>>>(si, sf, imp, sab, keep);
        k_gather<<<kB * kBAND, 384, 0, stream>>>(cur, oth, keep, si);
        k_commit<<<1, 64, 0, stream>>>(si);
        { float* tmp = cur; cur = oth; oth = tmp; }

        // ---- main layer on pruned tokens ----
        k_ln<<<kB * kBAND, 384, 0, stream>>>(cur, xn, l1w, l1b, si, 0);
        k_gemm<<<dim3(197, 18), 256, 0, stream>>>(xn, kD, qw, qb, qkv, 1152, (const float*)nullptr,
                                                  kD, kBAND, si, 0, 0, 0);
        k_attn<<<kB * kH * kBAND, 64, 0, stream>>>(qkv, obuf, si);
        k_gemm<<<dim3(197, 6), 256, 0, stream>>>(obuf, kD, pw, pb, cur, kD, cur,
                                                 kD, kBAND, si, 0, 0, 0);
        k_ln<<<kB * kBAND, 384, 0, stream>>>(cur, xn, l2w, l2b, si, 0);
        k_gemm<<<dim3(197, 24), 256, 0, stream>>>(xn, kD, f1w, f1b, hbuf, 1536, (const float*)nullptr,
                                                  kD, kBAND, si, 0, 1, 0);
        k_gemm<<<dim3(197, 6), 256, 0, stream>>>(hbuf, 1536, f2w, f2b, cur, kD, cur,
                                                 1536, kBAND, si, 0, 0, 0);
    }

    k_lncls<<<kB, 384, 0, stream>>>(cur, normw, normb, xnm);
    k_head<<<kB * 4, 256, 0, stream>>>(xnm, headw, headb, out);
}

// Round 2
// 2025.443 us; speedup vs baseline: 2.8190x; 2.8190x over previous
//
#include <hip/hip_runtime.h>
#include <hip/hip_bf16.h>

// ---------------- constants ----------------
static constexpr int kL = 12;
static constexpr int kD = 384;
static constexpr int kH = 6;
static constexpr int kB = 64;
static constexpr int kNP = 196;      // patches
static constexpr int kBAND = 197;    // tokens incl cls (max)
static constexpr int kNCLS = 1000;
static constexpr float kSCALE = 0.125f;   // 64^-0.5
static constexpr float kEPS = 1e-6f;

typedef __attribute__((ext_vector_type(8))) short short8;
typedef __attribute__((ext_vector_type(4))) float f32x4;

__device__ __forceinline__ float gelu_f(float x) {
    return 0.5f * x * (1.0f + erff(x * 0.70710678118654752440f));
}

// ---------------- state init ----------------
__global__ __launch_bounds__(64) void k_init(int* si, float* sf) {
    if (threadIdx.x == 0) { si[0] = kBAND; sf[0] = 1.0f; }
}

// ---------------- fp32 -> bf16 weight conversion ----------------
__global__ __launch_bounds__(256) void k_cvt4(const float* __restrict__ src,
                                              __hip_bfloat16* __restrict__ dst, int n4) {
    int i = blockIdx.x * 256 + threadIdx.x;
    int stride = gridDim.x * 256;
    for (; i < n4; i += stride) {
        float4 v = ((const float4*)src)[i];
        dst[4 * i + 0] = __float2bfloat16(v.x);
        dst[4 * i + 1] = __float2bfloat16(v.y);
        dst[4 * i + 2] = __float2bfloat16(v.z);
        dst[4 * i + 3] = __float2bfloat16(v.w);
    }
}

// ---------------- im2col for patch embed (bf16 out) ----------------
__global__ __launch_bounds__(256) void k_im2col(const float* __restrict__ x, __hip_bfloat16* __restrict__ A) {
    int pt = blockIdx.x;              // b*196 + t
    int b = pt / kNP, t = pt - b * kNP;
    int py = t / 14, px = t - py * 14;
    const float* xb = x + (size_t)b * 3 * 224 * 224;
    __hip_bfloat16* arow = A + (size_t)pt * 768;
    for (int k = threadIdx.x; k < 768; k += 256) {
        int c = k >> 8;
        int r = k & 255;
        int ky = r >> 4, kx = r & 15;
        arow[k] = __float2bfloat16(xb[((size_t)c * 224 + py * 16 + ky) * 224 + px * 16 + kx]);
    }
}

// ---------------- assemble xt = [cls; patches] + pos (fp32) ----------------
__global__ __launch_bounds__(384) void k_assemble(const float* __restrict__ xp,
                                                  const float* __restrict__ patch_b,
                                                  const float* __restrict__ cls,
                                                  const float* __restrict__ pos,
                                                  float* __restrict__ xt) {
    int t = blockIdx.x % kBAND, b = blockIdx.x / kBAND;
    int c = threadIdx.x;
    float v;
    if (t == 0) v = cls[c] + pos[c];
    else v = xp[((size_t)(b * kNP + t - 1)) * kD + c] + patch_b[c] + pos[(size_t)t * kD + c];
    xt[((size_t)b * kBAND + t) * kD + c] = v;
}

// ---------------- bf16 MFMA GEMM ----------------
// C[row][col] = act(sum_k A[row][k]*W[col][k] + bias[col]) (+ R[row][col])
// Virtual row compaction: valid rows rv in [0, 64*Nt), mapping rv -> (b=rv/Nt, t=rv%Nt),
// physical row = b*band + t.  A,W are bf16 (as ushort), C fp32 or bf16.
template<int OUT_BF16, int ACT_GELU>
__global__ __launch_bounds__(256) void k_mgemm(
    const unsigned short* __restrict__ A, int lda,
    const unsigned short* __restrict__ W, int K,
    const float* __restrict__ bias,
    void* __restrict__ Cv, int ldc,
    const float* __restrict__ R,
    int band, const int* __restrict__ NtPtr, int ntConst)
{
    __shared__ __align__(16) unsigned short As[64][72];
    __shared__ __align__(16) unsigned short Ws[64][72];
    int Nt = NtPtr ? NtPtr[0] : ntConst;
    unsigned int rowsTotal = (unsigned int)kB * (unsigned int)Nt;
    unsigned int r0 = blockIdx.x * 64;
    int n0 = blockIdx.y * 64;
    if (r0 >= rowsTotal) return;

    int tid = threadIdx.x;
    int srow = tid >> 3;            // 0..31
    int scol = (tid & 7) << 3;      // 0..56 step 8

    // A source rows (virtual -> physical)
    const unsigned short* ap0 = nullptr;
    const unsigned short* ap1 = nullptr;
    unsigned int rv0 = r0 + srow, rv1 = r0 + srow + 32;
    bool v0 = rv0 < rowsTotal, v1 = rv1 < rowsTotal;
    if (v0) { unsigned int bb = rv0 / (unsigned int)Nt; unsigned int tt = rv0 - bb * Nt;
              ap0 = A + ((size_t)bb * band + tt) * lda; }
    if (v1) { unsigned int bb = rv1 / (unsigned int)Nt; unsigned int tt = rv1 - bb * Nt;
              ap1 = A + ((size_t)bb * band + tt) * lda; }
    const unsigned short* wp0 = W + (size_t)(n0 + srow) * K;
    const unsigned short* wp1 = W + (size_t)(n0 + srow + 32) * K;

    int wave = tid >> 6, lane = tid & 63;
    int wr32 = ((wave >> 1) & 1) * 32, wc32 = (wave & 1) * 32;
    int l15 = lane & 15, l4 = lane >> 4;

    f32x4 acc00 = {}, acc01 = {}, acc10 = {}, acc11 = {};

    for (int k0 = 0; k0 < K; k0 += 64) {
        uint4 zero = make_uint4(0, 0, 0, 0);
        uint4 a0 = v0 ? *(const uint4*)(ap0 + k0 + scol) : zero;
        uint4 a1 = v1 ? *(const uint4*)(ap1 + k0 + scol) : zero;
        uint4 w0 = *(const uint4*)(wp0 + k0 + scol);
        uint4 w1 = *(const uint4*)(wp1 + k0 + scol);
        __syncthreads();
        *(uint4*)&As[srow][scol] = a0;
        *(uint4*)&As[srow + 32][scol] = a1;
        *(uint4*)&Ws[srow][scol] = w0;
        *(uint4*)&Ws[srow + 32][scol] = w1;
        __syncthreads();
#pragma unroll
        for (int ks = 0; ks < 2; ++ks) {
            short8 af0 = *(const short8*)&As[wr32 + l15][ks * 32 + l4 * 8];
            short8 af1 = *(const short8*)&As[wr32 + 16 + l15][ks * 32 + l4 * 8];
            short8 bf0 = *(const short8*)&Ws[wc32 + l15][ks * 32 + l4 * 8];
            short8 bf1 = *(const short8*)&Ws[wc32 + 16 + l15][ks * 32 + l4 * 8];
            acc00 = __builtin_amdgcn_mfma_f32_16x16x32_bf16(af0, bf0, acc00, 0, 0, 0);
            acc01 = __builtin_amdgcn_mfma_f32_16x16x32_bf16(af0, bf1, acc01, 0, 0, 0);
            acc10 = __builtin_amdgcn_mfma_f32_16x16x32_bf16(af1, bf0, acc10, 0, 0, 0);
            acc11 = __builtin_amdgcn_mfma_f32_16x16x32_bf16(af1, bf1, acc11, 0, 0, 0);
        }
    }

    // epilogue: C col = lane&15, row = (lane>>4)*4 + reg   [m89-verified layout]
    f32x4 accs[2][2] = { { acc00, acc01 }, { acc10, acc11 } };
#pragma unroll
    for (int fi = 0; fi < 2; ++fi) {
        unsigned int rvb = r0 + wr32 + fi * 16 + l4 * 4;
#pragma unroll
        for (int fj = 0; fj < 2; ++fj) {
            int col = n0 + wc32 + fj * 16 + l15;
            float bv = bias ? bias[col] : 0.f;
#pragma unroll
            for (int r = 0; r < 4; ++r) {
                unsigned int rv = rvb + r;
                if (rv >= rowsTotal) continue;
                unsigned int bb = rv / (unsigned int)Nt;
                unsigned int tt = rv - bb * (unsigned int)Nt;
                size_t row = (size_t)bb * band + tt;
                float v = accs[fi][fj][r] + bv;
                if (ACT_GELU) v = gelu_f(v);
                if (R) v += R[row * ldc + col];
                if (OUT_BF16) ((__hip_bfloat16*)Cv)[row * ldc + col] = __float2bfloat16(v);
                else ((float*)Cv)[row * ldc + col] = v;
            }
        }
    }
}

// ---------------- LayerNorm over D=384 (bf16 out) ----------------
__global__ __launch_bounds__(384) void k_ln(const float* __restrict__ X, __hip_bfloat16* __restrict__ Y,
                                            const float* __restrict__ w, const float* __restrict__ b,
                                            const int* __restrict__ si) {
    int Nt = si[0];
    int t = blockIdx.x % kBAND, bb = blockIdx.x / kBAND;
    if (t >= Nt) return;
    int tid = threadIdx.x;
    const float* row = X + ((size_t)bb * kBAND + t) * kD;
    float v = row[tid];
    float s1 = v, s2 = v * v;
#pragma unroll
    for (int off = 32; off; off >>= 1) { s1 += __shfl_down(s1, off, 64); s2 += __shfl_down(s2, off, 64); }
    __shared__ float r1[8], r2[8];
    int wid = tid >> 6, lane = tid & 63;
    if (lane == 0) { r1[wid] = s1; r2[wid] = s2; }
    __syncthreads();
    float sum = r1[0] + r1[1] + r1[2] + r1[3] + r1[4] + r1[5];
    float sq = r2[0] + r2[1] + r2[2] + r2[3] + r2[4] + r2[5];
    float mu = sum * (1.f / 384.f);
    float var = fmaxf(sq * (1.f / 384.f) - mu * mu, 0.f);
    Y[((size_t)bb * kBAND + t) * kD + tid] = __float2bfloat16((v - mu) * rsqrtf(var + kEPS) * w[tid] + b[tid]);
}

// ---------------- LN of cls token only (fp32 out, final norm) ----------------
__global__ __launch_bounds__(384) void k_lncls(const float* __restrict__ X,
                                               const float* __restrict__ w, const float* __restrict__ b,
                                               float* __restrict__ Y) {
    int bb = blockIdx.x;
    int tid = threadIdx.x;
    const float* row = X + (size_t)bb * kBAND * kD;
    float v = row[tid];
    float s1 = v, s2 = v * v;
#pragma unroll
    for (int off = 32; off; off >>= 1) { s1 += __shfl_down(s1, off, 64); s2 += __shfl_down(s2, off, 64); }
    __shared__ float r1[8], r2[8];
    int wid = tid >> 6, lane = tid & 63;
    if (lane == 0) { r1[wid] = s1; r2[wid] = s2; }
    __syncthreads();
    float sum = r1[0] + r1[1] + r1[2] + r1[3] + r1[4] + r1[5];
    float sq = r2[0] + r2[1] + r2[2] + r2[3] + r2[4] + r2[5];
    float mu = sum * (1.f / 384.f);
    float var = fmaxf(sq * (1.f / 384.f) - mu * mu, 0.f);
    Y[(size_t)bb * kD + tid] = (v - mu) * rsqrtf(var + kEPS) * w[tid] + b[tid];
}

// ---------------- fused attention with keep-indirection (bf16 out) ----------------
__global__ __launch_bounds__(64) void k_attn(const float* __restrict__ qkv, __hip_bfloat16* __restrict__ o,
                                             const int* __restrict__ si, const int* __restrict__ keep) {
    int Nt = si[0];                       // NEW token count (post-dec3)
    int t = blockIdx.x % kBAND;
    int bh = blockIdx.x / kBAND;
    int h = bh % kH, b = bh / kH;
    if (t >= Nt) return;
    int lane = threadIdx.x;
    const float* base = qkv + (size_t)b * kBAND * 1152;
    __shared__ float qs[64];
    __shared__ float as[256];
    __shared__ int kidx[256];
#pragma unroll
    for (int i = 0; i < 4; i++) { int j = lane + (i << 6); kidx[j] = (j < Nt) ? keep[j] : 0; }
    __syncthreads();
    qs[lane] = base[(size_t)kidx[t] * 1152 + h * 64 + lane];
    __syncthreads();
    float sv[4];
    float m = -INFINITY;
#pragma unroll
    for (int i = 0; i < 4; i++) {
        int j = lane + (i << 6);
        float s = -INFINITY;
        if (j < Nt) {
            const float* krow = base + (size_t)kidx[j] * 1152 + 384 + h * 64;
            float acc = 0.f;
#pragma unroll
            for (int d = 0; d < 64; d += 4) {
                float4 k4 = *(const float4*)(krow + d);
                acc += qs[d] * k4.x + qs[d + 1] * k4.y + qs[d + 2] * k4.z + qs[d + 3] * k4.w;
            }
            s = acc * kSCALE;
        }
        sv[i] = s;
        m = fmaxf(m, s);
    }
#pragma unroll
    for (int off = 32; off; off >>= 1) m = fmaxf(m, __shfl_xor(m, off, 64));
    float sum = 0.f;
#pragma unroll
    for (int i = 0; i < 4; i++) {
        int j = lane + (i << 6);
        float e = (j < Nt) ? expf(sv[i] - m) : 0.f;
        sv[i] = e; sum += e;
    }
#pragma unroll
    for (int off = 32; off; off >>= 1) sum += __shfl_xor(sum, off, 64);
    float inv = 1.f / sum;
#pragma unroll
    for (int i = 0; i < 4; i++) { int j = lane + (i << 6); as[j] = sv[i] * inv; }
    __syncthreads();
    float acc = 0.f;
    const float* vbase = base + 768 + h * 64 + lane;
    for (int j = 0; j < Nt; j++) acc += as[j] * vbase[(size_t)kidx[j] * 1152];
    o[((size_t)b * kBAND + t) * kD + h * 64 + lane] = __float2bfloat16(acc);
}

// ---------------- decision stage 1: a_cls * vnorm per (b,h,j) ----------------
__global__ __launch_bounds__(256) void k_dec1(const float* __restrict__ qkv, float* __restrict__ imph,
                                              const int* __restrict__ si) {
    int Nt = si[0];
    if (Nt - 1 <= 16) return;
    int h = blockIdx.x % kH, b = blockIdx.x / kH;
    const float* base = qkv + (size_t)b * kBAND * 1152;
    __shared__ float qs[64];
    __shared__ float red[256];
    int tid = threadIdx.x;
    if (tid < 64) qs[tid] = base[h * 64 + tid];   // q of cls (token 0)
    __syncthreads();
    int j = tid;
    float s = -INFINITY, vn = 0.f, e = 0.f;
    if (j < Nt) {
        const float* krow = base + (size_t)j * 1152 + 384 + h * 64;
        const float* vrow = base + (size_t)j * 1152 + 768 + h * 64;
        float acc = 0.f, v2 = 0.f;
#pragma unroll
        for (int d = 0; d < 64; d += 4) {
            float4 k4 = *(const float4*)(krow + d);
            float4 v4 = *(const float4*)(vrow + d);
            acc += qs[d] * k4.x + qs[d + 1] * k4.y + qs[d + 2] * k4.z + qs[d + 3] * k4.w;
            v2 += v4.x * v4.x + v4.y * v4.y + v4.z * v4.z + v4.w * v4.w;
        }
        s = acc * kSCALE;
        vn = sqrtf(v2);
    }
    red[tid] = s; __syncthreads();
    for (int st = 128; st; st >>= 1) { if (tid < st) red[tid] = fmaxf(red[tid], red[tid + st]); __syncthreads(); }
    float m = red[0]; __syncthreads();
    e = (j < Nt) ? expf(s - m) : 0.f;
    red[tid] = e; __syncthreads();
    for (int st = 128; st; st >>= 1) { if (tid < st) red[tid] += red[tid + st]; __syncthreads(); }
    float inv = 1.f / red[0];
    if (j < Nt) imph[((size_t)b * kH + h) * kBAND + j] = e * inv * vn;
}

// ---------------- decision stage 2: imp + per-batch sums ----------------
__global__ __launch_bounds__(256) void k_dec2(const float* __restrict__ imph, float* __restrict__ imp,
                                              float* __restrict__ sab, const int* __restrict__ si) {
    int Nt = si[0];
    if (Nt - 1 <= 16) return;
    int b = blockIdx.x;
    int tid = threadIdx.x;
    __shared__ float red[256];
    float v = 0.f;
    if (tid < Nt) {
        float s = 0.f;
#pragma unroll
        for (int h = 0; h < kH; h++) s += imph[((size_t)b * kH + h) * kBAND + tid];
        v = s * (1.f / 6.f);
        imp[(size_t)b * kBAND + tid] = v;
    }
    red[tid] = v; __syncthreads();
    for (int st = 128; st; st >>= 1) { if (tid < st) red[tid] += red[tid + st]; __syncthreads(); }
    if (tid == 0) {
        float sa = red[0];
        float sp = sa - imp[(size_t)b * kBAND];
        sab[2 * b] = sa; sab[2 * b + 1] = sp;
    }
}

// ---------------- decision stage 3: mass, ratio, top-k, keep_idx, commit Nt ----------------
__global__ __launch_bounds__(256) void k_dec3(int* si, float* sf, const float* __restrict__ imp,
                                              const float* __restrict__ sab, int* keep) {
    int Nt = si[0];
    int tid = threadIdx.x;
    bool active = (Nt - 1 > 16);
    if (!active) {
        for (int j = tid; j < Nt; j += 256) keep[j] = j;
        return;                    // si[0] unchanged
    }
    int N = Nt - 1;
    __shared__ float red[256];
    __shared__ int ri[256];
    __shared__ float sc[200];
    __shared__ int flag[200];
    float v = 0.f;
    if (tid < kB) v = sab[2 * tid + 1] / (sab[2 * tid] + kEPS);
    red[tid] = v; __syncthreads();
    for (int st = 128; st; st >>= 1) { if (tid < st) red[tid] += red[tid + st]; __syncthreads(); }
    float mass = red[0] * (1.f / 64.f);
    float prev = sf[0];
    float ratio = 0.5f * mass / (prev + kEPS);
    ratio = fminf(fmaxf(ratio, 0.f), 1.f);
    int N_next = (int)((double)N * (double)ratio);
    if (N_next < 16) N_next = 16;
    if (tid == 0) sf[0] = mass;     // prev_mass updated whenever decision runs
    __syncthreads();
    if (N_next >= N) {
        for (int j = tid; j < Nt; j += 256) keep[j] = j;
        return;                    // si[0] unchanged
    }
    for (int j = tid; j < N; j += 256) {
        float s = 0.f;
        for (int b = 0; b < kB; b++) s += imp[(size_t)b * kBAND + j + 1];
        sc[j] = s * (1.f / 64.f);
        flag[j] = 0;
    }
    __syncthreads();
    for (int it = 0; it < N_next; ++it) {
        float mv = (tid < N) ? sc[tid] : -INFINITY;
        int mi = tid;
        red[tid] = mv; ri[tid] = mi; __syncthreads();
        for (int st = 128; st; st >>= 1) {
            if (tid < st) {
                float ov = red[tid + st]; int oi = ri[tid + st];
                if (ov > red[tid] || (ov == red[tid] && oi < ri[tid])) { red[tid] = ov; ri[tid] = oi; }
            }
            __syncthreads();
        }
        if (tid == 0) { flag[ri[0]] = 1; sc[ri[0]] = -INFINITY; }
        __syncthreads();
    }
    if (tid == 0) {
        keep[0] = 0;
        int pos = 1;
        for (int j = 0; j < N; j++) if (flag[j]) keep[pos++] = j + 1;
        si[0] = N_next + 1;        // commit new token count
    }
}

// ---------------- gather tokens (fp32 residual stream) ----------------
__global__ __launch_bounds__(384) void k_gather(const float* __restrict__ src, float* __restrict__ dst,
                                                const int* __restrict__ keep, const int* __restrict__ si) {
    int NtNew = si[0];
    int t = blockIdx.x % kBAND, b = blockIdx.x / kBAND;
    if (t >= NtNew) return;
    int sj = keep[t];
    dst[((size_t)b * kBAND + t) * kD + threadIdx.x] = src[((size_t)b * kBAND + sj) * kD + threadIdx.x];
}

// ---------------- head ----------------
__global__ __launch_bounds__(256) void k_head(const float* __restrict__ xn, const float* __restrict__ hw,
                                              const float* __restrict__ hb, float* __restrict__ out) {
    int b = blockIdx.x >> 2;
    int n = ((blockIdx.x & 3) << 8) + threadIdx.x;
    __shared__ float xs[384];
    for (int i = threadIdx.x; i < 384; i += 256) xs[i] = xn[(size_t)b * kD + i];
    __syncthreads();
    if (n >= kNCLS) return;
    const float* wrow = hw + (size_t)n * kD;
    float acc = 0.f;
#pragma unroll 8
    for (int d = 0; d < kD; d += 4) {
        float4 w4 = *(const float4*)(wrow + d);
        acc += xs[d] * w4.x + xs[d + 1] * w4.y + xs[d + 2] * w4.z + xs[d + 3] * w4.w;
    }
    out[(size_t)b * kNCLS + n] = acc + hb[n];
}

// ---------------- host launch ----------------
extern "C" void kernel_launch(void* const* d_in, const int* in_sizes, int n_in,
                              void* d_out, int out_size, void* d_ws, size_t ws_size,
                              hipStream_t stream) {
    const float* x       = (const float*)d_in[0];
    const float* patch_w = (const float*)d_in[1];
    const float* patch_b = (const float*)d_in[2];
    const float* cls_tok = (const float*)d_in[3];
    const float* pos     = (const float*)d_in[4];
    const float* ln1w    = (const float*)d_in[5];
    const float* ln1b    = (const float*)d_in[6];
    const float* qkvw    = (const float*)d_in[7];
    const float* qkvb    = (const float*)d_in[8];
    const float* projw   = (const float*)d_in[9];
    const float* projb   = (const float*)d_in[10];
    const float* ln2w    = (const float*)d_in[11];
    const float* ln2b    = (const float*)d_in[12];
    const float* fc1w    = (const float*)d_in[13];
    const float* fc1b    = (const float*)d_in[14];
    const float* fc2w    = (const float*)d_in[15];
    const float* fc2b    = (const float*)d_in[16];
    const float* normw   = (const float*)d_in[17];
    const float* normb   = (const float*)d_in[18];
    const float* headw   = (const float*)d_in[19];
    const float* headb   = (const float*)d_in[20];
    float* out = (float*)d_out;

    char* ws = (char*)d_ws;
    const size_t MB = 1024ull * 1024ull;
    int*   si   = (int*)ws;
    float* sf   = (float*)(ws + 64);
    int*   keep = (int*)(ws + 256);
    float* imph = (float*)(ws + 4096);
    float* imp  = (float*)(ws + 360448);
    float* sab  = (float*)(ws + 417792);
    float* xnm  = (float*)(ws + 425984);
    float* xtA  = (float*)(ws + 1 * MB);
    float* xtB  = (float*)(ws + 21 * MB);
    __hip_bfloat16* xn   = (__hip_bfloat16*)(ws + 41 * MB);   // aliased: attn out (obuf)
    float* qkv  = (float*)(ws + 51 * MB);                     // aliased: xp (patch GEMM out)
    __hip_bfloat16* hbuf = (__hip_bfloat16*)(ws + 110 * MB);  // aliased: im2col bf16 buffer
    __hip_bfloat16* wpat = (__hip_bfloat16*)(ws + 149 * MB);
    __hip_bfloat16* wqkv = (__hip_bfloat16*)(ws + 150 * MB);
    __hip_bfloat16* wprj = (__hip_bfloat16*)(ws + 161 * MB);
    __hip_bfloat16* wfc1 = (__hip_bfloat16*)(ws + 165 * MB);
    __hip_bfloat16* wfc2 = (__hip_bfloat16*)(ws + 180 * MB);
    __hip_bfloat16* Aim  = hbuf;
    __hip_bfloat16* obuf = xn;
    float* xp = qkv;

    k_init<<<1, 64, 0, stream>>>(si, sf);
    // weight conversion (fp32 -> bf16), every call (deterministic)
    k_cvt4<<<512, 256, 0, stream>>>(patch_w, wpat, 294912 / 4);
    k_cvt4<<<512, 256, 0, stream>>>(qkvw, wqkv, 5308416 / 4);
    k_cvt4<<<512, 256, 0, stream>>>(projw, wprj, 1769472 / 4);
    k_cvt4<<<512, 256, 0, stream>>>(fc1w, wfc1, 7077888 / 4);
    k_cvt4<<<512, 256, 0, stream>>>(fc2w, wfc2, 7077888 / 4);

    k_im2col<<<kB * kNP, 256, 0, stream>>>(x, Aim);
    // patch embed: M=12544 (band=196, Nt=196), K=768, N=384 -> xp fp32
    k_mgemm<0, 0><<<dim3(196, 6), 256, 0, stream>>>(
        (const unsigned short*)Aim, 768, (const unsigned short*)wpat, 768,
        (const float*)nullptr, xp, kD, (const float*)nullptr, 196, (const int*)nullptr, 196);
    k_assemble<<<kB * kBAND, 384, 0, stream>>>(xp, patch_b, cls_tok, pos, xtA);

    float* cur = xtA; float* oth = xtB;
    for (int l = 0; l < kL; ++l) {
        const float* l1w = ln1w + l * kD;  const float* l1b = ln1b + l * kD;
        const __hip_bfloat16* qw = wqkv + (size_t)l * 1152 * kD;
        const float* qb = qkvb + l * 1152;
        const __hip_bfloat16* pw = wprj + (size_t)l * kD * kD;
        const float* pb = projb + l * kD;
        const float* l2w = ln2w + l * kD;  const float* l2b = ln2b + l * kD;
        const __hip_bfloat16* f1w = wfc1 + (size_t)l * 1536 * kD;
        const float* f1b = fc1b + l * 1536;
        const __hip_bfloat16* f2w = wfc2 + (size_t)l * kD * 1536;
        const float* f2b = fc2b + l * kD;

        // single LN + qkv GEMM (serves both decision and main path)
        k_ln<<<kB * kBAND, 384, 0, stream>>>(cur, xn, l1w, l1b, si);
        k_mgemm<0, 0><<<dim3(197, 18), 256, 0, stream>>>(
            (const unsigned short*)xn, kD, (const unsigned short*)qw, kD,
            qb, qkv, 1152, (const float*)nullptr, kBAND, si, 0);
        // pruning decision (device-gated)
        k_dec1<<<kB * kH, 256, 0, stream>>>(qkv, imph, si);
        k_dec2<<<kB, 256, 0, stream>>>(imph, imp, sab, si);
        k_dec3<<<1, 256, 0, stream>>>(si, sf, imp, sab, keep);   // commits new Nt into si[0]
        // gather residual stream; attention reads qkv through keep[]
        k_gather<<<kB * kBAND, 384, 0, stream>>>(cur, oth, keep, si);
        { float* tmp = cur; cur = oth; oth = tmp; }
        k_attn<<<kB * kH * kBAND, 64, 0, stream>>>(qkv, obuf, si, keep);
        // proj (+residual, in-place on cur)
        k_mgemm<0, 0><<<dim3(197, 6), 256, 0, stream>>>(
            (const unsigned short*)obuf, kD, (const unsigned short*)pw, kD,
            pb, cur, kD, cur, kBAND, si, 0);
        // MLP
        k_ln<<<kB * kBAND, 384, 0, stream>>>(cur, xn, l2w, l2b, si);
        k_mgemm<1, 1><<<dim3(197, 24), 256, 0, stream>>>(
            (const unsigned short*)xn, kD, (const unsigned short*)f1w, kD,
            f1b, hbuf, 1536, (const float*)nullptr, kBAND, si, 0);
        k_mgemm<0, 0><<<dim3(197, 6), 256, 0, stream>>>(
            (const unsigned short*)hbuf, 1536, (const unsigned short*)f2w, 1536,
            f2b, cur, kD, cur, kBAND, si, 0);
    }

    k_lncls<<<kB, 384, 0, stream>>>(cur, normw, normb, xnm);
    k_head<<<kB * 4, 256, 0, stream>>>(xnm, headw, headb, out);
}

// Round 3
// 1656.249 us; speedup vs baseline: 3.4474x; 1.2229x over previous
//
#include <hip/hip_runtime.h>
#include <hip/hip_bf16.h>

// ---------------- constants ----------------
static constexpr int kL = 12;
static constexpr int kD = 384;
static constexpr int kH = 6;
static constexpr int kB = 64;
static constexpr int kNP = 196;      // patches
static constexpr int kBAND = 197;    // tokens incl cls (max)
static constexpr int kNCLS = 1000;
static constexpr float kSCALE = 0.125f;   // 64^-0.5
static constexpr float kEPS = 1e-6f;
static constexpr size_t kWQ = (size_t)kB * kH * kBAND * 64;   // per-tensor elems in split qkv

typedef __attribute__((ext_vector_type(8))) short short8;
typedef __attribute__((ext_vector_type(4))) float f32x4;

__device__ __forceinline__ float gelu_f(float x) {
    return 0.5f * x * (1.0f + erff(x * 0.70710678118654752440f));
}
__device__ __forceinline__ unsigned short f2bf(float x) {
    __hip_bfloat16 h = __float2bfloat16(x);
    return *(unsigned short*)&h;
}

// ---------------- state init ----------------
__global__ __launch_bounds__(64) void k_init(int* si, float* sf) {
    if (threadIdx.x == 0) { si[0] = kBAND; sf[0] = 1.0f; }
}

// ---------------- fp32 -> bf16 weight conversion ----------------
__global__ __launch_bounds__(256) void k_cvt4(const float* __restrict__ src,
                                              __hip_bfloat16* __restrict__ dst, int n4) {
    int i = blockIdx.x * 256 + threadIdx.x;
    int stride = gridDim.x * 256;
    for (; i < n4; i += stride) {
        float4 v = ((const float4*)src)[i];
        dst[4 * i + 0] = __float2bfloat16(v.x);
        dst[4 * i + 1] = __float2bfloat16(v.y);
        dst[4 * i + 2] = __float2bfloat16(v.z);
        dst[4 * i + 3] = __float2bfloat16(v.w);
    }
}

// ---------------- im2col for patch embed (bf16 out) ----------------
__global__ __launch_bounds__(256) void k_im2col(const float* __restrict__ x, __hip_bfloat16* __restrict__ A) {
    int pt = blockIdx.x;              // b*196 + t
    int b = pt / kNP, t = pt - b * kNP;
    int py = t / 14, px = t - py * 14;
    const float* xb = x + (size_t)b * 3 * 224 * 224;
    __hip_bfloat16* arow = A + (size_t)pt * 768;
    for (int k = threadIdx.x; k < 768; k += 256) {
        int c = k >> 8;
        int r = k & 255;
        int ky = r >> 4, kx = r & 15;
        arow[k] = __float2bfloat16(xb[((size_t)c * 224 + py * 16 + ky) * 224 + px * 16 + kx]);
    }
}

// ---------------- assemble xt = [cls; patches] + pos (fp32) ----------------
__global__ __launch_bounds__(384) void k_assemble(const float* __restrict__ xp,
                                                  const float* __restrict__ patch_b,
                                                  const float* __restrict__ cls,
                                                  const float* __restrict__ pos,
                                                  float* __restrict__ xt) {
    int t = blockIdx.x % kBAND, b = blockIdx.x / kBAND;
    int c = threadIdx.x;
    float v;
    if (t == 0) v = cls[c] + pos[c];
    else v = xp[((size_t)(b * kNP + t - 1)) * kD + c] + patch_b[c] + pos[(size_t)t * kD + c];
    xt[((size_t)b * kBAND + t) * kD + c] = v;
}

// ---------------- bf16 MFMA GEMM ----------------
// C[row][col] = act(sum_k A[row][k]*W[col][k] + bias[col]) (+ R[rrow][col])
// Virtual row compaction over valid rows rv in [0, 64*Nt): rv -> (b=rv/Nt, t=rv%Nt),
// physical row = b*band + t.  R row optionally indirected through keepR (pruning fuse).
// QKV: additionally emit bf16 head-split copies into qsplit[which][b*H+h][t][64].
template<int OUT_BF16, int ACT_GELU, int QKV>
__global__ __launch_bounds__(256) void k_mgemm(
    const unsigned short* __restrict__ A, int lda,
    const unsigned short* __restrict__ W, int K,
    const float* __restrict__ bias,
    void* __restrict__ Cv, int ldc,
    const float* __restrict__ R,
    const int* __restrict__ keepR,
    int band, const int* __restrict__ NtPtr, int ntConst,
    __hip_bfloat16* __restrict__ qsplit)
{
    __shared__ __align__(16) unsigned short As[64][72];
    __shared__ __align__(16) unsigned short Ws[64][72];
    int Nt = NtPtr ? NtPtr[0] : ntConst;
    unsigned int rowsTotal = (unsigned int)kB * (unsigned int)Nt;
    unsigned int r0 = blockIdx.x * 64;
    int n0 = blockIdx.y * 64;
    if (r0 >= rowsTotal) return;

    int tid = threadIdx.x;
    int srow = tid >> 3;            // 0..31
    int scol = (tid & 7) << 3;      // 0..56 step 8

    const unsigned short* ap0 = nullptr;
    const unsigned short* ap1 = nullptr;
    unsigned int rv0 = r0 + srow, rv1 = r0 + srow + 32;
    bool v0 = rv0 < rowsTotal, v1 = rv1 < rowsTotal;
    if (v0) { unsigned int bb = rv0 / (unsigned int)Nt; unsigned int tt = rv0 - bb * Nt;
              ap0 = A + ((size_t)bb * band + tt) * lda; }
    if (v1) { unsigned int bb = rv1 / (unsigned int)Nt; unsigned int tt = rv1 - bb * Nt;
              ap1 = A + ((size_t)bb * band + tt) * lda; }
    const unsigned short* wp0 = W + (size_t)(n0 + srow) * K;
    const unsigned short* wp1 = W + (size_t)(n0 + srow + 32) * K;

    int wave = tid >> 6, lane = tid & 63;
    int wr32 = ((wave >> 1) & 1) * 32, wc32 = (wave & 1) * 32;
    int l15 = lane & 15, l4 = lane >> 4;

    f32x4 acc00 = {}, acc01 = {}, acc10 = {}, acc11 = {};

    for (int k0 = 0; k0 < K; k0 += 64) {
        uint4 zero = make_uint4(0, 0, 0, 0);
        uint4 a0 = v0 ? *(const uint4*)(ap0 + k0 + scol) : zero;
        uint4 a1 = v1 ? *(const uint4*)(ap1 + k0 + scol) : zero;
        uint4 w0 = *(const uint4*)(wp0 + k0 + scol);
        uint4 w1 = *(const uint4*)(wp1 + k0 + scol);
        __syncthreads();
        *(uint4*)&As[srow][scol] = a0;
        *(uint4*)&As[srow + 32][scol] = a1;
        *(uint4*)&Ws[srow][scol] = w0;
        *(uint4*)&Ws[srow + 32][scol] = w1;
        __syncthreads();
#pragma unroll
        for (int ks = 0; ks < 2; ++ks) {
            short8 af0 = *(const short8*)&As[wr32 + l15][ks * 32 + l4 * 8];
            short8 af1 = *(const short8*)&As[wr32 + 16 + l15][ks * 32 + l4 * 8];
            short8 bf0 = *(const short8*)&Ws[wc32 + l15][ks * 32 + l4 * 8];
            short8 bf1 = *(const short8*)&Ws[wc32 + 16 + l15][ks * 32 + l4 * 8];
            acc00 = __builtin_amdgcn_mfma_f32_16x16x32_bf16(af0, bf0, acc00, 0, 0, 0);
            acc01 = __builtin_amdgcn_mfma_f32_16x16x32_bf16(af0, bf1, acc01, 0, 0, 0);
            acc10 = __builtin_amdgcn_mfma_f32_16x16x32_bf16(af1, bf0, acc10, 0, 0, 0);
            acc11 = __builtin_amdgcn_mfma_f32_16x16x32_bf16(af1, bf1, acc11, 0, 0, 0);
        }
    }

    f32x4 accs[2][2] = { { acc00, acc01 }, { acc10, acc11 } };
#pragma unroll
    for (int fi = 0; fi < 2; ++fi) {
        unsigned int rvb = r0 + wr32 + fi * 16 + l4 * 4;
#pragma unroll
        for (int fj = 0; fj < 2; ++fj) {
            int col = n0 + wc32 + fj * 16 + l15;
            float bv = bias ? bias[col] : 0.f;
#pragma unroll
            for (int r = 0; r < 4; ++r) {
                unsigned int rv = rvb + r;
                if (rv >= rowsTotal) continue;
                unsigned int bb = rv / (unsigned int)Nt;
                unsigned int tt = rv - bb * (unsigned int)Nt;
                size_t row = (size_t)bb * band + tt;
                float v = accs[fi][fj][r] + bv;
                if (ACT_GELU) v = gelu_f(v);
                if (R) {
                    size_t rrow = keepR ? ((size_t)bb * band + keepR[tt]) : row;
                    v += R[rrow * ldc + col];
                }
                if (OUT_BF16) ((__hip_bfloat16*)Cv)[row * ldc + col] = __float2bfloat16(v);
                else ((float*)Cv)[row * ldc + col] = v;
                if (QKV) {
                    int which = col >= 768 ? 2 : (col >= 384 ? 1 : 0);
                    int hc = col - which * 384;
                    int hh = hc >> 6, dd = hc & 63;
                    qsplit[(size_t)which * kWQ + (((size_t)bb * kH + hh) * kBAND + tt) * 64 + dd] =
                        __float2bfloat16(v);
                }
            }
        }
    }
}

// ---------------- LayerNorm over D=384 (bf16 out) ----------------
__global__ __launch_bounds__(384) void k_ln(const float* __restrict__ X, __hip_bfloat16* __restrict__ Y,
                                            const float* __restrict__ w, const float* __restrict__ b,
                                            const int* __restrict__ si) {
    int Nt = si[0];
    int t = blockIdx.x % kBAND, bb = blockIdx.x / kBAND;
    if (t >= Nt) return;
    int tid = threadIdx.x;
    const float* row = X + ((size_t)bb * kBAND + t) * kD;
    float v = row[tid];
    float s1 = v, s2 = v * v;
#pragma unroll
    for (int off = 32; off; off >>= 1) { s1 += __shfl_down(s1, off, 64); s2 += __shfl_down(s2, off, 64); }
    __shared__ float r1[8], r2[8];
    int wid = tid >> 6, lane = tid & 63;
    if (lane == 0) { r1[wid] = s1; r2[wid] = s2; }
    __syncthreads();
    float sum = r1[0] + r1[1] + r1[2] + r1[3] + r1[4] + r1[5];
    float sq = r2[0] + r2[1] + r2[2] + r2[3] + r2[4] + r2[5];
    float mu = sum * (1.f / 384.f);
    float var = fmaxf(sq * (1.f / 384.f) - mu * mu, 0.f);
    Y[((size_t)bb * kBAND + t) * kD + tid] = __float2bfloat16((v - mu) * rsqrtf(var + kEPS) * w[tid] + b[tid]);
}

// ---------------- LN of cls token only (fp32 out, final norm) ----------------
__global__ __launch_bounds__(384) void k_lncls(const float* __restrict__ X,
                                               const float* __restrict__ w, const float* __restrict__ b,
                                               float* __restrict__ Y) {
    int bb = blockIdx.x;
    int tid = threadIdx.x;
    const float* row = X + (size_t)bb * kBAND * kD;
    float v = row[tid];
    float s1 = v, s2 = v * v;
#pragma unroll
    for (int off = 32; off; off >>= 1) { s1 += __shfl_down(s1, off, 64); s2 += __shfl_down(s2, off, 64); }
    __shared__ float r1[8], r2[8];
    int wid = tid >> 6, lane = tid & 63;
    if (lane == 0) { r1[wid] = s1; r2[wid] = s2; }
    __syncthreads();
    float sum = r1[0] + r1[1] + r1[2] + r1[3] + r1[4] + r1[5];
    float sq = r2[0] + r2[1] + r2[2] + r2[3] + r2[4] + r2[5];
    float mu = sum * (1.f / 384.f);
    float var = fmaxf(sq * (1.f / 384.f) - mu * mu, 0.f);
    Y[(size_t)bb * kD + tid] = (v - mu) * rsqrtf(var + kEPS) * w[tid] + b[tid];
}

// ---------------- MFMA flash attention: one block per (b,h) ----------------
// Reads bf16 split q/k/v via keep[] (old token indices), writes bf16 O at new rows.
__global__ __launch_bounds__(256) void k_attn2(const __hip_bfloat16* __restrict__ qsplit,
                                               __hip_bfloat16* __restrict__ o,
                                               const int* __restrict__ si,
                                               const int* __restrict__ keep) {
    __shared__ __align__(16) unsigned short Kb[224][72];
    __shared__ __align__(16) unsigned short Vt[64][228];
    __shared__ __align__(16) unsigned short Pb[4][16][228];
    int Nt = si[0];
    int bh = blockIdx.x;
    int b = bh / kH, h = bh - b * kH;
    int tid = threadIdx.x, w = tid >> 6, lane = tid & 63;
    int l15 = lane & 15, l4 = lane >> 4;
    int nJT = (Nt + 15) >> 4;
    int nKT = (Nt + 31) >> 5;
    int NTP = nKT << 5;

    const unsigned short* qb = (const unsigned short*)qsplit + (size_t)bh * kBAND * 64;
    const unsigned short* kb = (const unsigned short*)qsplit + kWQ + (size_t)bh * kBAND * 64;
    const unsigned short* vb = (const unsigned short*)qsplit + 2 * kWQ + (size_t)bh * kBAND * 64;

    // stage K (row-major) and V (transposed), zero-padded to NTP rows
    {
        int rr = tid >> 3;
        int c8 = (tid & 7) << 3;
        for (int r = rr; r < NTP; r += 32) {
            uint4 kv = make_uint4(0, 0, 0, 0), vv = make_uint4(0, 0, 0, 0);
            if (r < Nt) {
                int old = keep[r];
                kv = *(const uint4*)(kb + ((size_t)old << 6) + c8);
                vv = *(const uint4*)(vb + ((size_t)old << 6) + c8);
            }
            *(uint4*)&Kb[r][c8] = kv;
            const unsigned short* vs = (const unsigned short*)&vv;
#pragma unroll
            for (int e = 0; e < 8; ++e) Vt[c8 + e][r] = vs[e];
        }
    }
    __syncthreads();

    for (int strip = w; strip < nJT; strip += 4) {
        int tq = (strip << 4) + l15;
        int told = (tq < Nt) ? keep[tq] : 0;
        const unsigned short* qrow = qb + ((size_t)told << 6) + (l4 << 3);
        short8 qf0 = *(const short8*)(qrow);
        short8 qf1 = *(const short8*)(qrow + 32);

        f32x4 sv[13];
#pragma unroll
        for (int jt = 0; jt < 13; ++jt) {
            if (jt < nJT) {
                const unsigned short* kr = &Kb[(jt << 4) + l15][l4 << 3];
                short8 kf0 = *(const short8*)(kr);
                short8 kf1 = *(const short8*)(kr + 32);
                f32x4 a = {};
                a = __builtin_amdgcn_mfma_f32_16x16x32_bf16(qf0, kf0, a, 0, 0, 0);
                a = __builtin_amdgcn_mfma_f32_16x16x32_bf16(qf1, kf1, a, 0, 0, 0);
                sv[jt] = a;
            }
        }
        // scale + mask + row max (rows live in 16-lane groups)
        float mx[4] = { -INFINITY, -INFINITY, -INFINITY, -INFINITY };
#pragma unroll
        for (int jt = 0; jt < 13; ++jt) if (jt < nJT) {
            bool ok = ((jt << 4) + l15) < Nt;
#pragma unroll
            for (int r = 0; r < 4; ++r) {
                float s = ok ? sv[jt][r] * kSCALE : -INFINITY;
                sv[jt][r] = s;
                mx[r] = fmaxf(mx[r], s);
            }
        }
#pragma unroll
        for (int r = 0; r < 4; ++r) {
            mx[r] = fmaxf(mx[r], __shfl_xor(mx[r], 1, 64));
            mx[r] = fmaxf(mx[r], __shfl_xor(mx[r], 2, 64));
            mx[r] = fmaxf(mx[r], __shfl_xor(mx[r], 4, 64));
            mx[r] = fmaxf(mx[r], __shfl_xor(mx[r], 8, 64));
        }
        float sm[4] = { 0.f, 0.f, 0.f, 0.f };
#pragma unroll
        for (int jt = 0; jt < 13; ++jt) if (jt < nJT) {
#pragma unroll
            for (int r = 0; r < 4; ++r) {
                float p = expf(sv[jt][r] - mx[r]);
                sv[jt][r] = p;
                sm[r] += p;
            }
        }
#pragma unroll
        for (int r = 0; r < 4; ++r) {
            sm[r] += __shfl_xor(sm[r], 1, 64);
            sm[r] += __shfl_xor(sm[r], 2, 64);
            sm[r] += __shfl_xor(sm[r], 4, 64);
            sm[r] += __shfl_xor(sm[r], 8, 64);
            sm[r] = 1.f / sm[r];
        }
        // write normalized P (bf16) into per-wave LDS; zero pad cols
#pragma unroll
        for (int jt = 0; jt < 13; ++jt) if (jt < nJT) {
#pragma unroll
            for (int r = 0; r < 4; ++r)
                Pb[w][(l4 << 2) + r][(jt << 4) + l15] = f2bf(sv[jt][r] * sm[r]);
        }
        for (int c = (nJT << 4) + lane; c < NTP; c += 64) {
#pragma unroll
            for (int rr2 = 0; rr2 < 16; ++rr2) Pb[w][rr2][c] = 0;
        }
        asm volatile("s_waitcnt lgkmcnt(0)" ::: "memory");
        __builtin_amdgcn_sched_barrier(0);

        f32x4 oacc[4] = { {}, {}, {}, {} };
#pragma unroll
        for (int kt = 0; kt < 7; ++kt) if (kt < nKT) {
            short8 pf = *(const short8*)&Pb[w][l15][(kt << 5) + (l4 << 3)];
#pragma unroll
            for (int dt = 0; dt < 4; ++dt) {
                short8 vf = *(const short8*)&Vt[(dt << 4) + l15][(kt << 5) + (l4 << 3)];
                oacc[dt] = __builtin_amdgcn_mfma_f32_16x16x32_bf16(pf, vf, oacc[dt], 0, 0, 0);
            }
        }
#pragma unroll
        for (int dt = 0; dt < 4; ++dt) {
#pragma unroll
            for (int r = 0; r < 4; ++r) {
                int tqo = (strip << 4) + (l4 << 2) + r;
                if (tqo < Nt)
                    o[((size_t)b * kBAND + tqo) * kD + h * 64 + (dt << 4) + l15] =
                        __float2bfloat16(oacc[dt][r]);
            }
        }
    }
}

// ---------------- decision A: per-batch importance (fused dec1+dec2) ----------------
__global__ __launch_bounds__(256) void k_decA(const float* __restrict__ qkv, float* __restrict__ imp,
                                              float* __restrict__ sab, const int* __restrict__ si) {
    int Nt = si[0];
    if (Nt - 1 <= 16) return;
    int b = blockIdx.x;
    int tid = threadIdx.x;
    const float* base = qkv + (size_t)b * kBAND * 1152;
    __shared__ float qs[64];
    __shared__ float red[256];
    int j = tid;
    float acc6 = 0.f;
    for (int h = 0; h < kH; ++h) {
        if (tid < 64) qs[tid] = base[h * 64 + tid];
        __syncthreads();
        float s = -INFINITY, vn = 0.f;
        if (j < Nt) {
            const float* krow = base + (size_t)j * 1152 + 384 + h * 64;
            const float* vrow = base + (size_t)j * 1152 + 768 + h * 64;
            float a = 0.f, v2 = 0.f;
#pragma unroll
            for (int d = 0; d < 64; d += 4) {
                float4 k4 = *(const float4*)(krow + d);
                float4 v4 = *(const float4*)(vrow + d);
                a += qs[d] * k4.x + qs[d + 1] * k4.y + qs[d + 2] * k4.z + qs[d + 3] * k4.w;
                v2 += v4.x * v4.x + v4.y * v4.y + v4.z * v4.z + v4.w * v4.w;
            }
            s = a * kSCALE;
            vn = sqrtf(v2);
        }
        red[tid] = s; __syncthreads();
        for (int st = 128; st; st >>= 1) { if (tid < st) red[tid] = fmaxf(red[tid], red[tid + st]); __syncthreads(); }
        float m = red[0]; __syncthreads();
        float e = (j < Nt) ? expf(s - m) : 0.f;
        red[tid] = e; __syncthreads();
        for (int st = 128; st; st >>= 1) { if (tid < st) red[tid] += red[tid + st]; __syncthreads(); }
        float inv = 1.f / red[0];
        acc6 += e * inv * vn;
        __syncthreads();
    }
    float v = (j < Nt) ? acc6 * (1.f / 6.f) : 0.f;
    if (j < Nt) imp[(size_t)b * kBAND + j] = v;
    red[tid] = v; __syncthreads();
    for (int st = 128; st; st >>= 1) { if (tid < st) red[tid] += red[tid + st]; __syncthreads(); }
    if (tid == 0) {
        float sa = red[0];
        sab[2 * b] = sa;
        sab[2 * b + 1] = sa - v;   // tid==0 holds token-0 imp
    }
}

// ---------------- decision B: mass/ratio, rank-based top-k, keep, commit Nt ----------------
__global__ __launch_bounds__(256) void k_decB(int* si, float* sf, const float* __restrict__ imp,
                                              const float* __restrict__ sab, int* keep) {
    int Nt = si[0];
    int tid = threadIdx.x;
    if (Nt - 1 <= 16) {
        for (int jj = tid; jj < Nt; jj += 256) keep[jj] = jj;
        return;
    }
    int N = Nt - 1;
    __shared__ float red[256];
    __shared__ float sc[200];
    __shared__ int flag[200];
    float v = (tid < kB) ? sab[2 * tid + 1] / (sab[2 * tid] + kEPS) : 0.f;
    red[tid] = v; __syncthreads();
    for (int st = 128; st; st >>= 1) { if (tid < st) red[tid] += red[tid + st]; __syncthreads(); }
    float mass = red[0] * (1.f / 64.f);
    float prev = sf[0];
    float ratio = 0.5f * mass / (prev + kEPS);
    ratio = fminf(fmaxf(ratio, 0.f), 1.f);
    int N_next = (int)((double)N * (double)ratio);
    if (N_next < 16) N_next = 16;
    if (tid == 0) sf[0] = mass;
    __syncthreads();
    if (N_next >= N) {
        for (int jj = tid; jj < Nt; jj += 256) keep[jj] = jj;
        return;
    }
    if (tid < N) {
        float s = 0.f;
        for (int b = 0; b < kB; ++b) s += imp[(size_t)b * kBAND + tid + 1];
        sc[tid] = s;
    }
    __syncthreads();
    if (tid < N) {
        float s = sc[tid];
        int rank = 0;
        for (int i = 0; i < N; ++i) {
            float oth = sc[i];
            rank += (oth > s) || (oth == s && i < tid);
        }
        flag[tid] = (rank < N_next) ? 1 : 0;
    }
    __syncthreads();
    if (tid == 0) {
        keep[0] = 0;
        int pos = 1;
        for (int jj = 0; jj < N; ++jj) if (flag[jj]) keep[pos++] = jj + 1;
        si[0] = N_next + 1;
    }
}

// ---------------- head ----------------
__global__ __launch_bounds__(256) void k_head(const float* __restrict__ xn, const float* __restrict__ hw,
                                              const float* __restrict__ hb, float* __restrict__ out) {
    int b = blockIdx.x >> 2;
    int n = ((blockIdx.x & 3) << 8) + threadIdx.x;
    __shared__ float xs[384];
    for (int i = threadIdx.x; i < 384; i += 256) xs[i] = xn[(size_t)b * kD + i];
    __syncthreads();
    if (n >= kNCLS) return;
    const float* wrow = hw + (size_t)n * kD;
    float acc = 0.f;
#pragma unroll 8
    for (int d = 0; d < kD; d += 4) {
        float4 w4 = *(const float4*)(wrow + d);
        acc += xs[d] * w4.x + xs[d + 1] * w4.y + xs[d + 2] * w4.z + xs[d + 3] * w4.w;
    }
    out[(size_t)b * kNCLS + n] = acc + hb[n];
}

// ---------------- host launch ----------------
extern "C" void kernel_launch(void* const* d_in, const int* in_sizes, int n_in,
                              void* d_out, int out_size, void* d_ws, size_t ws_size,
                              hipStream_t stream) {
    const float* x       = (const float*)d_in[0];
    const float* patch_w = (const float*)d_in[1];
    const float* patch_b = (const float*)d_in[2];
    const float* cls_tok = (const float*)d_in[3];
    const float* pos     = (const float*)d_in[4];
    const float* ln1w    = (const float*)d_in[5];
    const float* ln1b    = (const float*)d_in[6];
    const float* qkvw    = (const float*)d_in[7];
    const float* qkvb    = (const float*)d_in[8];
    const float* projw   = (const float*)d_in[9];
    const float* projb   = (const float*)d_in[10];
    const float* ln2w    = (const float*)d_in[11];
    const float* ln2b    = (const float*)d_in[12];
    const float* fc1w    = (const float*)d_in[13];
    const float* fc1b    = (const float*)d_in[14];
    const float* fc2w    = (const float*)d_in[15];
    const float* fc2b    = (const float*)d_in[16];
    const float* normw   = (const float*)d_in[17];
    const float* normb   = (const float*)d_in[18];
    const float* headw   = (const float*)d_in[19];
    const float* headb   = (const float*)d_in[20];
    float* out = (float*)d_out;

    char* ws = (char*)d_ws;
    const size_t MB = 1024ull * 1024ull;
    int*   si   = (int*)ws;
    float* sf   = (float*)(ws + 64);
    int*   keep = (int*)(ws + 256);
    float* imp  = (float*)(ws + 4096);                 // 64*197 f32 ~ 50 KB
    float* sab  = (float*)(ws + 128 * 1024);
    float* xnm  = (float*)(ws + 256 * 1024);           // 64*384 f32 ~ 98 KB
    float* xtA  = (float*)(ws + 1 * MB);               // 19.4 MB
    float* xtB  = (float*)(ws + 21 * MB);              // 19.4 MB
    __hip_bfloat16* xn   = (__hip_bfloat16*)(ws + 41 * MB);   // 9.7 MB; aliased: attn out
    float* qkv  = (float*)(ws + 51 * MB);                     // 58.1 MB; aliased: hbuf / Aim / xp
    __hip_bfloat16* qsplit = (__hip_bfloat16*)(ws + 110 * MB); // 29 MB
    __hip_bfloat16* wpat = (__hip_bfloat16*)(ws + 140 * MB);
    __hip_bfloat16* wqkv = (__hip_bfloat16*)(ws + 141 * MB);
    __hip_bfloat16* wprj = (__hip_bfloat16*)(ws + 152 * MB);
    __hip_bfloat16* wfc1 = (__hip_bfloat16*)(ws + 156 * MB);
    __hip_bfloat16* wfc2 = (__hip_bfloat16*)(ws + 171 * MB);
    __hip_bfloat16* hbuf = (__hip_bfloat16*)(ws + 51 * MB);   // fc1 out, aliases qkv (disjoint lifetime)
    __hip_bfloat16* Aim  = (__hip_bfloat16*)(ws + 51 * MB);   // im2col, dead before layer 0
    float* xp  = (float*)(ws + 80 * MB);                      // patch GEMM out, dead before layer 0
    __hip_bfloat16* obuf = xn;

    k_init<<<1, 64, 0, stream>>>(si, sf);
    k_cvt4<<<512, 256, 0, stream>>>(patch_w, wpat, 294912 / 4);
    k_cvt4<<<512, 256, 0, stream>>>(qkvw, wqkv, 5308416 / 4);
    k_cvt4<<<512, 256, 0, stream>>>(projw, wprj, 1769472 / 4);
    k_cvt4<<<512, 256, 0, stream>>>(fc1w, wfc1, 7077888 / 4);
    k_cvt4<<<512, 256, 0, stream>>>(fc2w, wfc2, 7077888 / 4);

    k_im2col<<<kB * kNP, 256, 0, stream>>>(x, Aim);
    k_mgemm<0, 0, 0><<<dim3(196, 6), 256, 0, stream>>>(
        (const unsigned short*)Aim, 768, (const unsigned short*)wpat, 768,
        (const float*)nullptr, xp, kD, (const float*)nullptr, (const int*)nullptr,
        196, (const int*)nullptr, 196, (__hip_bfloat16*)nullptr);
    k_assemble<<<kB * kBAND, 384, 0, stream>>>(xp, patch_b, cls_tok, pos, xtA);

    float* cur = xtA; float* oth = xtB;
    for (int l = 0; l < kL; ++l) {
        const float* l1w = ln1w + l * kD;  const float* l1b = ln1b + l * kD;
        const __hip_bfloat16* qw = wqkv + (size_t)l * 1152 * kD;
        const float* qb = qkvb + l * 1152;
        const __hip_bfloat16* pw = wprj + (size_t)l * kD * kD;
        const float* pb = projb + l * kD;
        const float* l2w = ln2w + l * kD;  const float* l2b = ln2b + l * kD;
        const __hip_bfloat16* f1w = wfc1 + (size_t)l * 1536 * kD;
        const float* f1b = fc1b + l * 1536;
        const __hip_bfloat16* f2w = wfc2 + (size_t)l * kD * 1536;
        const float* f2b = fc2b + l * kD;

        // LN + qkv GEMM on OLD token set (serves decision and, via keep, attention)
        k_ln<<<kB * kBAND, 384, 0, stream>>>(cur, xn, l1w, l1b, si);
        k_mgemm<0, 0, 1><<<dim3(197, 18), 256, 0, stream>>>(
            (const unsigned short*)xn, kD, (const unsigned short*)qw, kD,
            qb, qkv, 1152, (const float*)nullptr, (const int*)nullptr,
            kBAND, si, 0, qsplit);
        // decision (device-gated); decB commits new Nt into si[0]
        k_decA<<<kB, 256, 0, stream>>>(qkv, imp, sab, si);
        k_decB<<<1, 256, 0, stream>>>(si, sf, imp, sab, keep);
        // attention on pruned tokens (reads q/k/v via keep)
        k_attn2<<<kB * kH, 256, 0, stream>>>(qsplit, obuf, si, keep);
        // proj + pruned-residual (gather fused via keep), write to other buffer
        k_mgemm<0, 0, 0><<<dim3(197, 6), 256, 0, stream>>>(
            (const unsigned short*)obuf, kD, (const unsigned short*)pw, kD,
            pb, oth, kD, cur, keep, kBAND, si, 0, (__hip_bfloat16*)nullptr);
        { float* tmp = cur; cur = oth; oth = tmp; }
        // MLP
        k_ln<<<kB * kBAND, 384, 0, stream>>>(cur, xn, l2w, l2b, si);
        k_mgemm<1, 1, 0><<<dim3(197, 24), 256, 0, stream>>>(
            (const unsigned short*)xn, kD, (const unsigned short*)f1w, kD,
            f1b, hbuf, 1536, (const float*)nullptr, (const int*)nullptr,
            kBAND, si, 0, (__hip_bfloat16*)nullptr);
        k_mgemm<0, 0, 0><<<dim3(197, 6), 256, 0, stream>>>(
            (const unsigned short*)hbuf, 1536, (const unsigned short*)f2w, 1536,
            f2b, cur, kD, cur, (const int*)nullptr, kBAND, si, 0, (__hip_bfloat16*)nullptr);
    }

    k_lncls<<<kB, 384, 0, stream>>>(cur, normw, normb, xnm);
    k_head<<<kB * 4, 256, 0, stream>>>(xnm, headw, headb, out);
}

// Round 4
// 1489.944 us; speedup vs baseline: 3.8322x; 1.1116x over previous
//
#include <hip/hip_runtime.h>
#include <hip/hip_bf16.h>

// ---------------- constants ----------------
static constexpr int kL = 12;
static constexpr int kD = 384;
static constexpr int kH = 6;
static constexpr int kB = 64;
static constexpr int kNP = 196;      // patches
static constexpr int kBAND = 197;    // tokens incl cls (max)
static constexpr int kNCLS = 1000;
static constexpr float kSCALE = 0.125f;   // 64^-0.5
static constexpr float kEPS = 1e-6f;
static constexpr size_t kWQ = (size_t)kB * kH * kBAND * 64;   // per-tensor elems in split qkv

typedef __attribute__((ext_vector_type(8))) short short8;
typedef __attribute__((ext_vector_type(4))) float f32x4;

__device__ __forceinline__ float gelu_f(float x) {
    return 0.5f * x * (1.0f + erff(x * 0.70710678118654752440f));
}
__device__ __forceinline__ unsigned short f2bf(float x) {
    __hip_bfloat16 h = __float2bfloat16(x);
    return *(unsigned short*)&h;
}

// ---------------- state init ----------------
__global__ __launch_bounds__(64) void k_init(int* si, float* sf) {
    if (threadIdx.x == 0) { si[0] = kBAND; sf[0] = 1.0f; }
}

// ---------------- fp32 -> bf16 weight conversion ----------------
__global__ __launch_bounds__(256) void k_cvt4(const float* __restrict__ src,
                                              __hip_bfloat16* __restrict__ dst, int n4) {
    int i = blockIdx.x * 256 + threadIdx.x;
    int stride = gridDim.x * 256;
    for (; i < n4; i += stride) {
        float4 v = ((const float4*)src)[i];
        dst[4 * i + 0] = __float2bfloat16(v.x);
        dst[4 * i + 1] = __float2bfloat16(v.y);
        dst[4 * i + 2] = __float2bfloat16(v.z);
        dst[4 * i + 3] = __float2bfloat16(v.w);
    }
}

// ---------------- im2col for patch embed (bf16 out) ----------------
__global__ __launch_bounds__(256) void k_im2col(const float* __restrict__ x, __hip_bfloat16* __restrict__ A) {
    int pt = blockIdx.x;              // b*196 + t
    int b = pt / kNP, t = pt - b * kNP;
    int py = t / 14, px = t - py * 14;
    const float* xb = x + (size_t)b * 3 * 224 * 224;
    __hip_bfloat16* arow = A + (size_t)pt * 768;
    for (int k = threadIdx.x; k < 768; k += 256) {
        int c = k >> 8;
        int r = k & 255;
        int ky = r >> 4, kx = r & 15;
        arow[k] = __float2bfloat16(xb[((size_t)c * 224 + py * 16 + ky) * 224 + px * 16 + kx]);
    }
}

// ---------------- assemble xt = [cls; patches] + pos (fp32) ----------------
__global__ __launch_bounds__(384) void k_assemble(const float* __restrict__ xp,
                                                  const float* __restrict__ patch_b,
                                                  const float* __restrict__ cls,
                                                  const float* __restrict__ pos,
                                                  float* __restrict__ xt) {
    int t = blockIdx.x % kBAND, b = blockIdx.x / kBAND;
    int c = threadIdx.x;
    float v;
    if (t == 0) v = cls[c] + pos[c];
    else v = xp[((size_t)(b * kNP + t - 1)) * kD + c] + patch_b[c] + pos[(size_t)t * kD + c];
    xt[((size_t)b * kBAND + t) * kD + c] = v;
}

// ---------------- bf16 MFMA GEMM, XCD-pinned block swizzle ----------------
// Grid is 1-D: L -> (xcd=L&7, n=(L>>3)%nT, r=((L>>3)/nT)*8+xcd).
// All n-tiles of a row-tile land on the same XCD (round-robin %8 heuristic) so
// each A-tile is HBM-fetched once; W stays L2-resident per XCD.
// C[row][col] = act(sum_k A[row][k]*W[col][k] + bias[col]) (+ R[rrow][col])
// Virtual row compaction over valid rows rv in [0, 64*Nt): rv -> (b=rv/Nt, t=rv%Nt),
// physical row = b*band + t.  R row optionally indirected through keepR (pruning fuse).
// QKV: C is the head-split fp32 layout q/k/v[bh][t][64] (ldc ignored for store).
template<int OUT_BF16, int ACT_GELU, int QKV>
__global__ __launch_bounds__(256) void k_mgemm(
    const unsigned short* __restrict__ A, int lda,
    const unsigned short* __restrict__ W, int K,
    const float* __restrict__ bias,
    void* __restrict__ Cv, int ldc,
    const float* __restrict__ R,
    const int* __restrict__ keepR,
    int rT, int nT, int band,
    const int* __restrict__ NtPtr, int ntConst)
{
    __shared__ __align__(16) unsigned short As[64][72];
    __shared__ __align__(16) unsigned short Ws[64][72];
    int Nt = NtPtr ? NtPtr[0] : ntConst;
    unsigned int rowsTotal = (unsigned int)kB * (unsigned int)Nt;

    int L = blockIdx.x;
    int xcd = L & 7;
    int m = L >> 3;
    int n = m % nT;
    int r = (m / nT) * 8 + xcd;
    if (r >= rT) return;
    unsigned int r0 = (unsigned int)r * 64;
    int n0 = n * 64;
    if (r0 >= rowsTotal) return;

    int tid = threadIdx.x;
    int srow = tid >> 3;            // 0..31
    int scol = (tid & 7) << 3;      // 0..56 step 8

    const unsigned short* ap0 = nullptr;
    const unsigned short* ap1 = nullptr;
    unsigned int rv0 = r0 + srow, rv1 = r0 + srow + 32;
    bool v0 = rv0 < rowsTotal, v1 = rv1 < rowsTotal;
    if (v0) { unsigned int bb = rv0 / (unsigned int)Nt; unsigned int tt = rv0 - bb * Nt;
              ap0 = A + ((size_t)bb * band + tt) * lda; }
    if (v1) { unsigned int bb = rv1 / (unsigned int)Nt; unsigned int tt = rv1 - bb * Nt;
              ap1 = A + ((size_t)bb * band + tt) * lda; }
    const unsigned short* wp0 = W + (size_t)(n0 + srow) * K;
    const unsigned short* wp1 = W + (size_t)(n0 + srow + 32) * K;

    int wave = tid >> 6, lane = tid & 63;
    int wr32 = ((wave >> 1) & 1) * 32, wc32 = (wave & 1) * 32;
    int l15 = lane & 15, l4 = lane >> 4;

    f32x4 acc00 = {}, acc01 = {}, acc10 = {}, acc11 = {};

    for (int k0 = 0; k0 < K; k0 += 64) {
        uint4 zero = make_uint4(0, 0, 0, 0);
        uint4 a0 = v0 ? *(const uint4*)(ap0 + k0 + scol) : zero;
        uint4 a1 = v1 ? *(const uint4*)(ap1 + k0 + scol) : zero;
        uint4 w0 = *(const uint4*)(wp0 + k0 + scol);
        uint4 w1 = *(const uint4*)(wp1 + k0 + scol);
        __syncthreads();
        *(uint4*)&As[srow][scol] = a0;
        *(uint4*)&As[srow + 32][scol] = a1;
        *(uint4*)&Ws[srow][scol] = w0;
        *(uint4*)&Ws[srow + 32][scol] = w1;
        __syncthreads();
#pragma unroll
        for (int ks = 0; ks < 2; ++ks) {
            short8 af0 = *(const short8*)&As[wr32 + l15][ks * 32 + l4 * 8];
            short8 af1 = *(const short8*)&As[wr32 + 16 + l15][ks * 32 + l4 * 8];
            short8 bf0 = *(const short8*)&Ws[wc32 + l15][ks * 32 + l4 * 8];
            short8 bf1 = *(const short8*)&Ws[wc32 + 16 + l15][ks * 32 + l4 * 8];
            acc00 = __builtin_amdgcn_mfma_f32_16x16x32_bf16(af0, bf0, acc00, 0, 0, 0);
            acc01 = __builtin_amdgcn_mfma_f32_16x16x32_bf16(af0, bf1, acc01, 0, 0, 0);
            acc10 = __builtin_amdgcn_mfma_f32_16x16x32_bf16(af1, bf0, acc10, 0, 0, 0);
            acc11 = __builtin_amdgcn_mfma_f32_16x16x32_bf16(af1, bf1, acc11, 0, 0, 0);
        }
    }

    f32x4 accs[2][2] = { { acc00, acc01 }, { acc10, acc11 } };
#pragma unroll
    for (int fi = 0; fi < 2; ++fi) {
        unsigned int rvb = r0 + wr32 + fi * 16 + l4 * 4;
#pragma unroll
        for (int fj = 0; fj < 2; ++fj) {
            int col = n0 + wc32 + fj * 16 + l15;
            float bv = bias ? bias[col] : 0.f;
#pragma unroll
            for (int rr = 0; rr < 4; ++rr) {
                unsigned int rv = rvb + rr;
                if (rv >= rowsTotal) continue;
                unsigned int bb = rv / (unsigned int)Nt;
                unsigned int tt = rv - bb * (unsigned int)Nt;
                size_t row = (size_t)bb * band + tt;
                float v = accs[fi][fj][rr] + bv;
                if (ACT_GELU) v = gelu_f(v);
                if (R) {
                    size_t rrow = keepR ? ((size_t)bb * band + keepR[tt]) : row;
                    v += R[rrow * ldc + col];
                }
                if (QKV) {
                    int which = col >= 768 ? 2 : (col >= 384 ? 1 : 0);
                    int hc = col - which * 384;
                    int hh = hc >> 6, dd = hc & 63;
                    ((float*)Cv)[(size_t)which * kWQ + (((size_t)bb * kH + hh) * kBAND + tt) * 64 + dd] = v;
                } else if (OUT_BF16) {
                    ((__hip_bfloat16*)Cv)[row * ldc + col] = __float2bfloat16(v);
                } else {
                    ((float*)Cv)[row * ldc + col] = v;
                }
            }
        }
    }
}

// ---------------- LayerNorm over D=384 (bf16 out) ----------------
__global__ __launch_bounds__(384) void k_ln(const float* __restrict__ X, __hip_bfloat16* __restrict__ Y,
                                            const float* __restrict__ w, const float* __restrict__ b,
                                            const int* __restrict__ si) {
    int Nt = si[0];
    int t = blockIdx.x % kBAND, bb = blockIdx.x / kBAND;
    if (t >= Nt) return;
    int tid = threadIdx.x;
    const float* row = X + ((size_t)bb * kBAND + t) * kD;
    float v = row[tid];
    float s1 = v, s2 = v * v;
#pragma unroll
    for (int off = 32; off; off >>= 1) { s1 += __shfl_down(s1, off, 64); s2 += __shfl_down(s2, off, 64); }
    __shared__ float r1[8], r2[8];
    int wid = tid >> 6, lane = tid & 63;
    if (lane == 0) { r1[wid] = s1; r2[wid] = s2; }
    __syncthreads();
    float sum = r1[0] + r1[1] + r1[2] + r1[3] + r1[4] + r1[5];
    float sq = r2[0] + r2[1] + r2[2] + r2[3] + r2[4] + r2[5];
    float mu = sum * (1.f / 384.f);
    float var = fmaxf(sq * (1.f / 384.f) - mu * mu, 0.f);
    Y[((size_t)bb * kBAND + t) * kD + tid] = __float2bfloat16((v - mu) * rsqrtf(var + kEPS) * w[tid] + b[tid]);
}

// ---------------- LN of cls token only (fp32 out, final norm) ----------------
__global__ __launch_bounds__(384) void k_lncls(const float* __restrict__ X,
                                               const float* __restrict__ w, const float* __restrict__ b,
                                               float* __restrict__ Y) {
    int bb = blockIdx.x;
    int tid = threadIdx.x;
    const float* row = X + (size_t)bb * kBAND * kD;
    float v = row[tid];
    float s1 = v, s2 = v * v;
#pragma unroll
    for (int off = 32; off; off >>= 1) { s1 += __shfl_down(s1, off, 64); s2 += __shfl_down(s2, off, 64); }
    __shared__ float r1[8], r2[8];
    int wid = tid >> 6, lane = tid & 63;
    if (lane == 0) { r1[wid] = s1; r2[wid] = s2; }
    __syncthreads();
    float sum = r1[0] + r1[1] + r1[2] + r1[3] + r1[4] + r1[5];
    float sq = r2[0] + r2[1] + r2[2] + r2[3] + r2[4] + r2[5];
    float mu = sum * (1.f / 384.f);
    float var = fmaxf(sq * (1.f / 384.f) - mu * mu, 0.f);
    Y[(size_t)bb * kD + tid] = (v - mu) * rsqrtf(var + kEPS) * w[tid] + b[tid];
}

// ---------------- MFMA flash attention: one block per (b,h) ----------------
// Reads fp32 split q/k/v via keep[] (old token indices), converts to bf16 while
// staging, writes bf16 O at new rows.
__global__ __launch_bounds__(256) void k_attn2(const float* __restrict__ qsplit,
                                               __hip_bfloat16* __restrict__ o,
                                               const int* __restrict__ si,
                                               const int* __restrict__ keep) {
    __shared__ __align__(16) unsigned short Kb[224][72];
    __shared__ __align__(16) unsigned short Vt[64][228];
    __shared__ __align__(16) unsigned short Pb[4][16][228];
    int Nt = si[0];
    int bh = blockIdx.x;
    int b = bh / kH, h = bh - b * kH;
    int tid = threadIdx.x, w = tid >> 6, lane = tid & 63;
    int l15 = lane & 15, l4 = lane >> 4;
    int nJT = (Nt + 15) >> 4;
    int nKT = (Nt + 31) >> 5;
    int NTP = nKT << 5;

    const float* qb = qsplit + (size_t)bh * kBAND * 64;
    const float* kb = qsplit + kWQ + (size_t)bh * kBAND * 64;
    const float* vb = qsplit + 2 * kWQ + (size_t)bh * kBAND * 64;

    // stage K (row-major) and V (transposed) as bf16, zero-padded to NTP rows
    {
        int rr = tid >> 3;
        int c8 = (tid & 7) << 3;
        for (int r = rr; r < NTP; r += 32) {
            unsigned short ks[8], vs[8];
#pragma unroll
            for (int e = 0; e < 8; ++e) { ks[e] = 0; vs[e] = 0; }
            if (r < Nt) {
                int old = keep[r];
                const float* kr = kb + ((size_t)old << 6) + c8;
                const float* vr = vb + ((size_t)old << 6) + c8;
                float4 k0 = *(const float4*)kr, k1 = *(const float4*)(kr + 4);
                float4 vv0 = *(const float4*)vr, vv1 = *(const float4*)(vr + 4);
                ks[0] = f2bf(k0.x); ks[1] = f2bf(k0.y); ks[2] = f2bf(k0.z); ks[3] = f2bf(k0.w);
                ks[4] = f2bf(k1.x); ks[5] = f2bf(k1.y); ks[6] = f2bf(k1.z); ks[7] = f2bf(k1.w);
                vs[0] = f2bf(vv0.x); vs[1] = f2bf(vv0.y); vs[2] = f2bf(vv0.z); vs[3] = f2bf(vv0.w);
                vs[4] = f2bf(vv1.x); vs[5] = f2bf(vv1.y); vs[6] = f2bf(vv1.z); vs[7] = f2bf(vv1.w);
            }
            *(uint4*)&Kb[r][c8] = *(uint4*)ks;
#pragma unroll
            for (int e = 0; e < 8; ++e) Vt[c8 + e][r] = vs[e];
        }
    }
    __syncthreads();

    for (int strip = w; strip < nJT; strip += 4) {
        int tq = (strip << 4) + l15;
        int told = (tq < Nt) ? keep[tq] : 0;
        const float* qrow = qb + ((size_t)told << 6) + (l4 << 3);
        float4 q0 = *(const float4*)(qrow),      q1 = *(const float4*)(qrow + 4);
        float4 q2 = *(const float4*)(qrow + 32), q3 = *(const float4*)(qrow + 36);
        unsigned short qa[8], qc[8];
        qa[0] = f2bf(q0.x); qa[1] = f2bf(q0.y); qa[2] = f2bf(q0.z); qa[3] = f2bf(q0.w);
        qa[4] = f2bf(q1.x); qa[5] = f2bf(q1.y); qa[6] = f2bf(q1.z); qa[7] = f2bf(q1.w);
        qc[0] = f2bf(q2.x); qc[1] = f2bf(q2.y); qc[2] = f2bf(q2.z); qc[3] = f2bf(q2.w);
        qc[4] = f2bf(q3.x); qc[5] = f2bf(q3.y); qc[6] = f2bf(q3.z); qc[7] = f2bf(q3.w);
        short8 qf0 = *(short8*)qa;
        short8 qf1 = *(short8*)qc;

        f32x4 sv[13];
#pragma unroll
        for (int jt = 0; jt < 13; ++jt) {
            if (jt < nJT) {
                const unsigned short* kr = &Kb[(jt << 4) + l15][l4 << 3];
                short8 kf0 = *(const short8*)(kr);
                short8 kf1 = *(const short8*)(kr + 32);
                f32x4 a = {};
                a = __builtin_amdgcn_mfma_f32_16x16x32_bf16(qf0, kf0, a, 0, 0, 0);
                a = __builtin_amdgcn_mfma_f32_16x16x32_bf16(qf1, kf1, a, 0, 0, 0);
                sv[jt] = a;
            }
        }
        float mx[4] = { -INFINITY, -INFINITY, -INFINITY, -INFINITY };
#pragma unroll
        for (int jt = 0; jt < 13; ++jt) if (jt < nJT) {
            bool ok = ((jt << 4) + l15) < Nt;
#pragma unroll
            for (int r = 0; r < 4; ++r) {
                float s = ok ? sv[jt][r] * kSCALE : -INFINITY;
                sv[jt][r] = s;
                mx[r] = fmaxf(mx[r], s);
            }
        }
#pragma unroll
        for (int r = 0; r < 4; ++r) {
            mx[r] = fmaxf(mx[r], __shfl_xor(mx[r], 1, 64));
            mx[r] = fmaxf(mx[r], __shfl_xor(mx[r], 2, 64));
            mx[r] = fmaxf(mx[r], __shfl_xor(mx[r], 4, 64));
            mx[r] = fmaxf(mx[r], __shfl_xor(mx[r], 8, 64));
        }
        float sm[4] = { 0.f, 0.f, 0.f, 0.f };
#pragma unroll
        for (int jt = 0; jt < 13; ++jt) if (jt < nJT) {
#pragma unroll
            for (int r = 0; r < 4; ++r) {
                float p = expf(sv[jt][r] - mx[r]);
                sv[jt][r] = p;
                sm[r] += p;
            }
        }
#pragma unroll
        for (int r = 0; r < 4; ++r) {
            sm[r] += __shfl_xor(sm[r], 1, 64);
            sm[r] += __shfl_xor(sm[r], 2, 64);
            sm[r] += __shfl_xor(sm[r], 4, 64);
            sm[r] += __shfl_xor(sm[r], 8, 64);
            sm[r] = 1.f / sm[r];
        }
#pragma unroll
        for (int jt = 0; jt < 13; ++jt) if (jt < nJT) {
#pragma unroll
            for (int r = 0; r < 4; ++r)
                Pb[w][(l4 << 2) + r][(jt << 4) + l15] = f2bf(sv[jt][r] * sm[r]);
        }
        for (int c = (nJT << 4) + lane; c < NTP; c += 64) {
#pragma unroll
            for (int rr2 = 0; rr2 < 16; ++rr2) Pb[w][rr2][c] = 0;
        }
        asm volatile("s_waitcnt lgkmcnt(0)" ::: "memory");
        __builtin_amdgcn_sched_barrier(0);

        f32x4 oacc[4] = { {}, {}, {}, {} };
#pragma unroll
        for (int kt = 0; kt < 7; ++kt) if (kt < nKT) {
            short8 pf = *(const short8*)&Pb[w][l15][(kt << 5) + (l4 << 3)];
#pragma unroll
            for (int dt = 0; dt < 4; ++dt) {
                short8 vf = *(const short8*)&Vt[(dt << 4) + l15][(kt << 5) + (l4 << 3)];
                oacc[dt] = __builtin_amdgcn_mfma_f32_16x16x32_bf16(pf, vf, oacc[dt], 0, 0, 0);
            }
        }
#pragma unroll
        for (int dt = 0; dt < 4; ++dt) {
#pragma unroll
            for (int r = 0; r < 4; ++r) {
                int tqo = (strip << 4) + (l4 << 2) + r;
                if (tqo < Nt)
                    o[((size_t)b * kBAND + tqo) * kD + h * 64 + (dt << 4) + l15] =
                        __float2bfloat16(oacc[dt][r]);
            }
        }
    }
}

// ---------------- decision A: per-batch importance (reads split fp32 qkv) ----------------
__global__ __launch_bounds__(256) void k_decA(const float* __restrict__ qsplit, float* __restrict__ imp,
                                              float* __restrict__ sab, const int* __restrict__ si) {
    int Nt = si[0];
    if (Nt - 1 <= 16) return;
    int b = blockIdx.x;
    int tid = threadIdx.x;
    __shared__ float qs[64];
    __shared__ float red[256];
    int j = tid;
    float acc6 = 0.f;
    for (int h = 0; h < kH; ++h) {
        size_t bh = (size_t)b * kH + h;
        const float* qp = qsplit + bh * kBAND * 64;
        const float* kp = qsplit + kWQ + bh * kBAND * 64;
        const float* vp = qsplit + 2 * kWQ + bh * kBAND * 64;
        if (tid < 64) qs[tid] = qp[tid];      // q of cls (token 0)
        __syncthreads();
        float s = -INFINITY, vn = 0.f;
        if (j < Nt) {
            const float* krow = kp + ((size_t)j << 6);
            const float* vrow = vp + ((size_t)j << 6);
            float a = 0.f, v2 = 0.f;
#pragma unroll
            for (int d = 0; d < 64; d += 4) {
                float4 k4 = *(const float4*)(krow + d);
                float4 v4 = *(const float4*)(vrow + d);
                a += qs[d] * k4.x + qs[d + 1] * k4.y + qs[d + 2] * k4.z + qs[d + 3] * k4.w;
                v2 += v4.x * v4.x + v4.y * v4.y + v4.z * v4.z + v4.w * v4.w;
            }
            s = a * kSCALE;
            vn = sqrtf(v2);
        }
        red[tid] = s; __syncthreads();
        for (int st = 128; st; st >>= 1) { if (tid < st) red[tid] = fmaxf(red[tid], red[tid + st]); __syncthreads(); }
        float m = red[0]; __syncthreads();
        float e = (j < Nt) ? expf(s - m) : 0.f;
        red[tid] = e; __syncthreads();
        for (int st = 128; st; st >>= 1) { if (tid < st) red[tid] += red[tid + st]; __syncthreads(); }
        float inv = 1.f / red[0];
        acc6 += e * inv * vn;
        __syncthreads();
    }
    float v = (j < Nt) ? acc6 * (1.f / 6.f) : 0.f;
    if (j < Nt) imp[(size_t)b * kBAND + j] = v;
    red[tid] = v; __syncthreads();
    for (int st = 128; st; st >>= 1) { if (tid < st) red[tid] += red[tid + st]; __syncthreads(); }
    if (tid == 0) {
        float sa = red[0];
        sab[2 * b] = sa;
        sab[2 * b + 1] = sa - v;   // tid==0 holds token-0 imp
    }
}

// ---------------- decision B: mass/ratio, rank-based top-k, keep, commit Nt ----------------
__global__ __launch_bounds__(256) void k_decB(int* si, float* sf, const float* __restrict__ imp,
                                              const float* __restrict__ sab, int* keep) {
    int Nt = si[0];
    int tid = threadIdx.x;
    if (Nt - 1 <= 16) {
        for (int jj = tid; jj < Nt; jj += 256) keep[jj] = jj;
        return;
    }
    int N = Nt - 1;
    __shared__ float red[256];
    __shared__ float sc[200];
    __shared__ int flag[200];
    float v = (tid < kB) ? sab[2 * tid + 1] / (sab[2 * tid] + kEPS) : 0.f;
    red[tid] = v; __syncthreads();
    for (int st = 128; st; st >>= 1) { if (tid < st) red[tid] += red[tid + st]; __syncthreads(); }
    float mass = red[0] * (1.f / 64.f);
    float prev = sf[0];
    float ratio = 0.5f * mass / (prev + kEPS);
    ratio = fminf(fmaxf(ratio, 0.f), 1.f);
    int N_next = (int)((double)N * (double)ratio);
    if (N_next < 16) N_next = 16;
    if (tid == 0) sf[0] = mass;
    __syncthreads();
    if (N_next >= N) {
        for (int jj = tid; jj < Nt; jj += 256) keep[jj] = jj;
        return;
    }
    if (tid < N) {
        float s = 0.f;
        for (int b = 0; b < kB; ++b) s += imp[(size_t)b * kBAND + tid + 1];
        sc[tid] = s;
    }
    __syncthreads();
    if (tid < N) {
        float s = sc[tid];
        int rank = 0;
        for (int i = 0; i < N; ++i) {
            float oth = sc[i];
            rank += (oth > s) || (oth == s && i < tid);
        }
        flag[tid] = (rank < N_next) ? 1 : 0;
    }
    __syncthreads();
    if (tid == 0) {
        keep[0] = 0;
        int pos = 1;
        for (int jj = 0; jj < N; ++jj) if (flag[jj]) keep[pos++] = jj + 1;
        si[0] = N_next + 1;
    }
}

// ---------------- head ----------------
__global__ __launch_bounds__(256) void k_head(const float* __restrict__ xn, const float* __restrict__ hw,
                                              const float* __restrict__ hb, float* __restrict__ out) {
    int b = blockIdx.x >> 2;
    int n = ((blockIdx.x & 3) << 8) + threadIdx.x;
    __shared__ float xs[384];
    for (int i = threadIdx.x; i < 384; i += 256) xs[i] = xn[(size_t)b * kD + i];
    __syncthreads();
    if (n >= kNCLS) return;
    const float* wrow = hw + (size_t)n * kD;
    float acc = 0.f;
#pragma unroll 8
    for (int d = 0; d < kD; d += 4) {
        float4 w4 = *(const float4*)(wrow + d);
        acc += xs[d] * w4.x + xs[d + 1] * w4.y + xs[d + 2] * w4.z + xs[d + 3] * w4.w;
    }
    out[(size_t)b * kNCLS + n] = acc + hb[n];
}

// ---------------- host launch ----------------
extern "C" void kernel_launch(void* const* d_in, const int* in_sizes, int n_in,
                              void* d_out, int out_size, void* d_ws, size_t ws_size,
                              hipStream_t stream) {
    const float* x       = (const float*)d_in[0];
    const float* patch_w = (const float*)d_in[1];
    const float* patch_b = (const float*)d_in[2];
    const float* cls_tok = (const float*)d_in[3];
    const float* pos     = (const float*)d_in[4];
    const float* ln1w    = (const float*)d_in[5];
    const float* ln1b    = (const float*)d_in[6];
    const float* qkvw    = (const float*)d_in[7];
    const float* qkvb    = (const float*)d_in[8];
    const float* projw   = (const float*)d_in[9];
    const float* projb   = (const float*)d_in[10];
    const float* ln2w    = (const float*)d_in[11];
    const float* ln2b    = (const float*)d_in[12];
    const float* fc1w    = (const float*)d_in[13];
    const float* fc1b    = (const float*)d_in[14];
    const float* fc2w    = (const float*)d_in[15];
    const float* fc2b    = (const float*)d_in[16];
    const float* normw   = (const float*)d_in[17];
    const float* normb   = (const float*)d_in[18];
    const float* headw   = (const float*)d_in[19];
    const float* headb   = (const float*)d_in[20];
    float* out = (float*)d_out;

    char* ws = (char*)d_ws;
    const size_t MB = 1024ull * 1024ull;
    int*   si   = (int*)ws;
    float* sf   = (float*)(ws + 64);
    int*   keep = (int*)(ws + 256);
    float* imp  = (float*)(ws + 4096);
    float* sab  = (float*)(ws + 128 * 1024);
    float* xnm  = (float*)(ws + 256 * 1024);
    float* xtA  = (float*)(ws + 1 * MB);                      // 19.4 MB
    float* xtB  = (float*)(ws + 21 * MB);                     // 19.4 MB
    __hip_bfloat16* xn   = (__hip_bfloat16*)(ws + 41 * MB);   // 9.7 MB; aliased: attn out
    // big region @51MB, aliased (disjoint lifetimes):
    //   pre-layers: Aim bf16 @51 (19.3), xp fp32 @71 (19.3)
    //   per-layer:  qsplit fp32 @51 (58.1) [qkv->attn], then hbuf bf16 @51 (38.7) [fc1->fc2]
    __hip_bfloat16* Aim    = (__hip_bfloat16*)(ws + 51 * MB);
    float*          xp     = (float*)(ws + 71 * MB);
    float*          qsplit = (float*)(ws + 51 * MB);
    __hip_bfloat16* hbuf   = (__hip_bfloat16*)(ws + 51 * MB);
    __hip_bfloat16* wpat = (__hip_bfloat16*)(ws + 110 * MB);
    __hip_bfloat16* wqkv = (__hip_bfloat16*)(ws + 111 * MB);
    __hip_bfloat16* wprj = (__hip_bfloat16*)(ws + 122 * MB);
    __hip_bfloat16* wfc1 = (__hip_bfloat16*)(ws + 126 * MB);
    __hip_bfloat16* wfc2 = (__hip_bfloat16*)(ws + 141 * MB);
    __hip_bfloat16* obuf = xn;

    k_init<<<1, 64, 0, stream>>>(si, sf);
    k_cvt4<<<512, 256, 0, stream>>>(patch_w, wpat, 294912 / 4);
    k_cvt4<<<512, 256, 0, stream>>>(qkvw, wqkv, 5308416 / 4);
    k_cvt4<<<512, 256, 0, stream>>>(projw, wprj, 1769472 / 4);
    k_cvt4<<<512, 256, 0, stream>>>(fc1w, wfc1, 7077888 / 4);
    k_cvt4<<<512, 256, 0, stream>>>(fc2w, wfc2, 7077888 / 4);

    k_im2col<<<kB * kNP, 256, 0, stream>>>(x, Aim);
    // patch embed: rT=196, nT=6, K=768 -> xp fp32
    k_mgemm<0, 0, 0><<<8 * 6 * 25, 256, 0, stream>>>(
        (const unsigned short*)Aim, 768, (const unsigned short*)wpat, 768,
        (const float*)nullptr, xp, kD, (const float*)nullptr, (const int*)nullptr,
        196, 6, 196, (const int*)nullptr, 196);
    k_assemble<<<kB * kBAND, 384, 0, stream>>>(xp, patch_b, cls_tok, pos, xtA);

    float* cur = xtA; float* oth = xtB;
    for (int l = 0; l < kL; ++l) {
        const float* l1w = ln1w + l * kD;  const float* l1b = ln1b + l * kD;
        const __hip_bfloat16* qw = wqkv + (size_t)l * 1152 * kD;
        const float* qb = qkvb + l * 1152;
        const __hip_bfloat16* pw = wprj + (size_t)l * kD * kD;
        const float* pb = projb + l * kD;
        const float* l2w = ln2w + l * kD;  const float* l2b = ln2b + l * kD;
        const __hip_bfloat16* f1w = wfc1 + (size_t)l * 1536 * kD;
        const float* f1b = fc1b + l * 1536;
        const __hip_bfloat16* f2w = wfc2 + (size_t)l * kD * 1536;
        const float* f2b = fc2b + l * kD;

        // LN + qkv GEMM on OLD token set -> split fp32 q/k/v
        k_ln<<<kB * kBAND, 384, 0, stream>>>(cur, xn, l1w, l1b, si);
        k_mgemm<0, 0, 1><<<8 * 18 * 25, 256, 0, stream>>>(
            (const unsigned short*)xn, kD, (const unsigned short*)qw, kD,
            qb, qsplit, 1152, (const float*)nullptr, (const int*)nullptr,
            197, 18, kBAND, si, 0);
        // decision (device-gated); decB commits new Nt into si[0]
        k_decA<<<kB, 256, 0, stream>>>(qsplit, imp, sab, si);
        k_decB<<<1, 256, 0, stream>>>(si, sf, imp, sab, keep);
        // attention on pruned tokens (reads q/k/v via keep)
        k_attn2<<<kB * kH, 256, 0, stream>>>(qsplit, obuf, si, keep);
        // proj + pruned-residual (gather fused via keep), write to other buffer
        k_mgemm<0, 0, 0><<<8 * 6 * 25, 256, 0, stream>>>(
            (const unsigned short*)obuf, kD, (const unsigned short*)pw, kD,
            pb, oth, kD, cur, keep, 197, 6, kBAND, si, 0);
        { float* tmp = cur; cur = oth; oth = tmp; }
        // MLP
        k_ln<<<kB * kBAND, 384, 0, stream>>>(cur, xn, l2w, l2b, si);
        k_mgemm<1, 1, 0><<<8 * 24 * 25, 256, 0, stream>>>(
            (const unsigned short*)xn, kD, (const unsigned short*)f1w, kD,
            f1b, hbuf, 1536, (const float*)nullptr, (const int*)nullptr,
            197, 24, kBAND, si, 0);
        k_mgemm<0, 0, 0><<<8 * 6 * 25, 256, 0, stream>>>(
            (const unsigned short*)hbuf, 1536, (const unsigned short*)f2w, 1536,
            f2b, cur, kD, cur, (const int*)nullptr, 197, 6, kBAND, si, 0);
    }

    k_lncls<<<kB, 384, 0, stream>>>(cur, normw, normb, xnm);
    k_head<<<kB * 4, 256, 0, stream>>>(xnm, headw, headb, out);
}

// Round 5
// 1378.521 us; speedup vs baseline: 4.1419x; 1.0808x over previous
//
#include <hip/hip_runtime.h>
#include <hip/hip_bf16.h>

// ---------------- constants ----------------
static constexpr int kL = 12;
static constexpr int kD = 384;
static constexpr int kH = 6;
static constexpr int kB = 64;
static constexpr int kNP = 196;      // patches
static constexpr int kBAND = 197;    // tokens incl cls (max)
static constexpr int kNCLS = 1000;
static constexpr float kSCALE = 0.125f;   // 64^-0.5
static constexpr float kEPS = 1e-6f;
static constexpr size_t kWQ = (size_t)kB * kH * kBAND * 64;   // per-tensor elems in split qkv

typedef __attribute__((ext_vector_type(8))) short short8;
typedef __attribute__((ext_vector_type(4))) float f32x4;

__device__ __forceinline__ float gelu_f(float x) {
    return 0.5f * x * (1.0f + erff(x * 0.70710678118654752440f));
}
__device__ __forceinline__ unsigned short f2bf(float x) {
    __hip_bfloat16 h = __float2bfloat16(x);
    return *(unsigned short*)&h;
}

// ---------------- state init ----------------
__global__ __launch_bounds__(64) void k_init(int* si, float* sf) {
    if (threadIdx.x == 0) { si[0] = kBAND; sf[0] = 1.0f; }
}

// ---------------- fp32 -> bf16 weight conversion (all 5 tensors, one launch) ----------------
__global__ __launch_bounds__(256) void k_cvtall(
    const float* __restrict__ s0, const float* __restrict__ s1, const float* __restrict__ s2,
    const float* __restrict__ s3, const float* __restrict__ s4,
    __hip_bfloat16* __restrict__ d0, __hip_bfloat16* __restrict__ d1, __hip_bfloat16* __restrict__ d2,
    __hip_bfloat16* __restrict__ d3, __hip_bfloat16* __restrict__ d4) {
    // sizes in float4 units
    const int c0 = 73728, c1 = 1400832, c2 = 1843200, c3 = 3612672, c4 = 5382144;
    int stride = gridDim.x * 256;
    for (int i = blockIdx.x * 256 + threadIdx.x; i < c4; i += stride) {
        const float* src; __hip_bfloat16* dst; int off;
        if (i < c0)      { src = s0; dst = d0; off = i; }
        else if (i < c1) { src = s1; dst = d1; off = i - c0; }
        else if (i < c2) { src = s2; dst = d2; off = i - c1; }
        else if (i < c3) { src = s3; dst = d3; off = i - c2; }
        else             { src = s4; dst = d4; off = i - c3; }
        float4 v = ((const float4*)src)[off];
        dst[4 * off + 0] = __float2bfloat16(v.x);
        dst[4 * off + 1] = __float2bfloat16(v.y);
        dst[4 * off + 2] = __float2bfloat16(v.z);
        dst[4 * off + 3] = __float2bfloat16(v.w);
    }
}

// ---------------- im2col for patch embed (bf16 out) ----------------
__global__ __launch_bounds__(256) void k_im2col(const float* __restrict__ x, __hip_bfloat16* __restrict__ A) {
    int pt = blockIdx.x;              // b*196 + t
    int b = pt / kNP, t = pt - b * kNP;
    int py = t / 14, px = t - py * 14;
    const float* xb = x + (size_t)b * 3 * 224 * 224;
    __hip_bfloat16* arow = A + (size_t)pt * 768;
    for (int k = threadIdx.x; k < 768; k += 256) {
        int c = k >> 8;
        int r = k & 255;
        int ky = r >> 4, kx = r & 15;
        arow[k] = __float2bfloat16(xb[((size_t)c * 224 + py * 16 + ky) * 224 + px * 16 + kx]);
    }
}

// ---------------- assemble xt = [cls; patches] + pos (fp32) ----------------
__global__ __launch_bounds__(384) void k_assemble(const float* __restrict__ xp,
                                                  const float* __restrict__ patch_b,
                                                  const float* __restrict__ cls,
                                                  const float* __restrict__ pos,
                                                  float* __restrict__ xt) {
    int t = blockIdx.x % kBAND, b = blockIdx.x / kBAND;
    int c = threadIdx.x;
    float v;
    if (t == 0) v = cls[c] + pos[c];
    else v = xp[((size_t)(b * kNP + t - 1)) * kD + c] + patch_b[c] + pos[(size_t)t * kD + c];
    xt[((size_t)b * kBAND + t) * kD + c] = v;
}

// ---------------- bf16 MFMA GEMM, XCD-pinned swizzle, LDS-staged coalesced epilogue ----------
// Grid 1-D: L -> (xcd=L&7, n=(L>>3)%nT, r=((L>>3)/nT)*8+xcd); all n-tiles of a row-tile
// land on one XCD so A is HBM-fetched once and W stays L2-resident.
// C[row][col] = act(sum_k A[row][k]*W[col][k] + bias[col]) (+ R[rrow][col])
// Virtual row compaction over rv in [0, 64*Nt): rv -> (b=rv/Nt, t=rv%Nt), phys row b*band+t.
// Epilogue: C tile staged in LDS (overlaying As/Ws), then coalesced row stores:
//   fp32: 16 lanes x float4 = 256B/row;  bf16: 8 lanes x 16B = 128B/row.
// QKV: C is head-split fp32 q/k/v[bh][t][64]; each row = one 256B contiguous run.
template<int OUT_BF16, int ACT_GELU, int QKV>
__global__ __launch_bounds__(256) void k_mgemm(
    const unsigned short* __restrict__ A, int lda,
    const unsigned short* __restrict__ W, int K,
    const float* __restrict__ bias,
    void* __restrict__ Cv, int ldc,
    const float* __restrict__ R,
    const int* __restrict__ keepR,
    int rT, int nT, int band,
    const int* __restrict__ NtPtr, int ntConst)
{
    __shared__ __align__(16) unsigned char pool[18432];
    unsigned short (*As)[72] = (unsigned short (*)[72])pool;            // 64x72 ushort = 9216B
    unsigned short (*Ws)[72] = (unsigned short (*)[72])(pool + 9216);   // 64x72 ushort = 9216B
    float (*Cs)[66] = (float (*)[66])pool;                              // 64x66 f32 = 16896B overlay
    unsigned short (*Cu)[76] = (unsigned short (*)[76])pool;            // 64x76 u16 = 9728B overlay

    int Nt = NtPtr ? NtPtr[0] : ntConst;
    unsigned int rowsTotal = (unsigned int)kB * (unsigned int)Nt;

    int L = blockIdx.x;
    int xcd = L & 7;
    int m = L >> 3;
    int n = m % nT;
    int r = (m / nT) * 8 + xcd;
    if (r >= rT) return;
    unsigned int r0 = (unsigned int)r * 64;
    int n0 = n * 64;
    if (r0 >= rowsTotal) return;

    int tid = threadIdx.x;
    int srow = tid >> 3;            // 0..31
    int scol = (tid & 7) << 3;      // 0..56 step 8

    const unsigned short* ap0 = nullptr;
    const unsigned short* ap1 = nullptr;
    unsigned int rv0 = r0 + srow, rv1 = r0 + srow + 32;
    bool v0 = rv0 < rowsTotal, v1 = rv1 < rowsTotal;
    if (v0) { unsigned int bb = rv0 / (unsigned int)Nt; unsigned int tt = rv0 - bb * Nt;
              ap0 = A + ((size_t)bb * band + tt) * lda; }
    if (v1) { unsigned int bb = rv1 / (unsigned int)Nt; unsigned int tt = rv1 - bb * Nt;
              ap1 = A + ((size_t)bb * band + tt) * lda; }
    const unsigned short* wp0 = W + (size_t)(n0 + srow) * K;
    const unsigned short* wp1 = W + (size_t)(n0 + srow + 32) * K;

    int wave = tid >> 6, lane = tid & 63;
    int wr32 = ((wave >> 1) & 1) * 32, wc32 = (wave & 1) * 32;
    int l15 = lane & 15, l4 = lane >> 4;

    f32x4 acc00 = {}, acc01 = {}, acc10 = {}, acc11 = {};

    for (int k0 = 0; k0 < K; k0 += 64) {
        uint4 zero = make_uint4(0, 0, 0, 0);
        uint4 a0 = v0 ? *(const uint4*)(ap0 + k0 + scol) : zero;
        uint4 a1 = v1 ? *(const uint4*)(ap1 + k0 + scol) : zero;
        uint4 w0 = *(const uint4*)(wp0 + k0 + scol);
        uint4 w1 = *(const uint4*)(wp1 + k0 + scol);
        __syncthreads();
        *(uint4*)&As[srow][scol] = a0;
        *(uint4*)&As[srow + 32][scol] = a1;
        *(uint4*)&Ws[srow][scol] = w0;
        *(uint4*)&Ws[srow + 32][scol] = w1;
        __syncthreads();
#pragma unroll
        for (int ks = 0; ks < 2; ++ks) {
            short8 af0 = *(const short8*)&As[wr32 + l15][ks * 32 + l4 * 8];
            short8 af1 = *(const short8*)&As[wr32 + 16 + l15][ks * 32 + l4 * 8];
            short8 bf0 = *(const short8*)&Ws[wc32 + l15][ks * 32 + l4 * 8];
            short8 bf1 = *(const short8*)&Ws[wc32 + 16 + l15][ks * 32 + l4 * 8];
            acc00 = __builtin_amdgcn_mfma_f32_16x16x32_bf16(af0, bf0, acc00, 0, 0, 0);
            acc01 = __builtin_amdgcn_mfma_f32_16x16x32_bf16(af0, bf1, acc01, 0, 0, 0);
            acc10 = __builtin_amdgcn_mfma_f32_16x16x32_bf16(af1, bf0, acc10, 0, 0, 0);
            acc11 = __builtin_amdgcn_mfma_f32_16x16x32_bf16(af1, bf1, acc11, 0, 0, 0);
        }
    }

    // -------- epilogue: bias/act/residual per element, stage tile in LDS --------
    __syncthreads();   // protect As/Ws before overlay
    f32x4 accs[2][2] = { { acc00, acc01 }, { acc10, acc11 } };
#pragma unroll
    for (int fi = 0; fi < 2; ++fi) {
        int lrow = wr32 + fi * 16 + l4 * 4;
        unsigned int rvb = r0 + lrow;
#pragma unroll
        for (int fj = 0; fj < 2; ++fj) {
            int lcol = wc32 + fj * 16 + l15;
            float bv = bias ? bias[n0 + lcol] : 0.f;
#pragma unroll
            for (int rr = 0; rr < 4; ++rr) {
                unsigned int rv = rvb + rr;
                float v = accs[fi][fj][rr] + bv;
                if (ACT_GELU) v = gelu_f(v);
                if (R && rv < rowsTotal) {
                    unsigned int bb = rv / (unsigned int)Nt;
                    unsigned int tt = rv - bb * (unsigned int)Nt;
                    size_t rrow = keepR ? ((size_t)bb * band + keepR[tt]) : ((size_t)bb * band + tt);
                    v += R[rrow * ldc + n0 + lcol];
                }
                if (OUT_BF16) Cu[lrow + rr][lcol] = f2bf(v);
                else          Cs[lrow + rr][lcol] = v;
            }
        }
    }
    __syncthreads();

    // -------- coalesced stores --------
    if (OUT_BF16) {
        // 64 rows x 8 chunks of 16B
#pragma unroll
        for (int i = 0; i < 2; ++i) {
            int id = tid + (i << 8);
            int row = id >> 3, c2 = id & 7;
            unsigned int rv = r0 + row;
            if (rv < rowsTotal) {
                unsigned int bb = rv / (unsigned int)Nt;
                unsigned int tt = rv - bb * (unsigned int)Nt;
                size_t prow = (size_t)bb * band + tt;
                uint4 val = *(const uint4*)&Cu[row][c2 << 3];
                *(uint4*)((__hip_bfloat16*)Cv + prow * ldc + n0 + (c2 << 3)) = val;
            }
        }
    } else {
        // 64 rows x 16 chunks of 16B (float4)
#pragma unroll
        for (int i = 0; i < 4; ++i) {
            int id = tid + (i << 8);
            int row = id >> 4, c4 = id & 15;
            unsigned int rv = r0 + row;
            if (rv < rowsTotal) {
                unsigned int bb = rv / (unsigned int)Nt;
                unsigned int tt = rv - bb * (unsigned int)Nt;
                float4 val = *(const float4*)&Cs[row][c4 << 2];
                if (QKV) {
                    int which = n0 >= 768 ? 2 : (n0 >= 384 ? 1 : 0);
                    int hh = (n0 - which * 384) >> 6;
                    *(float4*)((float*)Cv + (size_t)which * kWQ +
                               (((size_t)bb * kH + hh) * kBAND + tt) * 64 + (c4 << 2)) = val;
                } else {
                    *(float4*)((float*)Cv + ((size_t)bb * band + tt) * ldc + n0 + (c4 << 2)) = val;
                }
            }
        }
    }
}

// ---------------- LayerNorm over D=384 (bf16 out) ----------------
__global__ __launch_bounds__(384) void k_ln(const float* __restrict__ X, __hip_bfloat16* __restrict__ Y,
                                            const float* __restrict__ w, const float* __restrict__ b,
                                            const int* __restrict__ si) {
    int Nt = si[0];
    int t = blockIdx.x % kBAND, bb = blockIdx.x / kBAND;
    if (t >= Nt) return;
    int tid = threadIdx.x;
    const float* row = X + ((size_t)bb * kBAND + t) * kD;
    float v = row[tid];
    float s1 = v, s2 = v * v;
#pragma unroll
    for (int off = 32; off; off >>= 1) { s1 += __shfl_down(s1, off, 64); s2 += __shfl_down(s2, off, 64); }
    __shared__ float r1[8], r2[8];
    int wid = tid >> 6, lane = tid & 63;
    if (lane == 0) { r1[wid] = s1; r2[wid] = s2; }
    __syncthreads();
    float sum = r1[0] + r1[1] + r1[2] + r1[3] + r1[4] + r1[5];
    float sq = r2[0] + r2[1] + r2[2] + r2[3] + r2[4] + r2[5];
    float mu = sum * (1.f / 384.f);
    float var = fmaxf(sq * (1.f / 384.f) - mu * mu, 0.f);
    Y[((size_t)bb * kBAND + t) * kD + tid] = __float2bfloat16((v - mu) * rsqrtf(var + kEPS) * w[tid] + b[tid]);
}

// ---------------- LN of cls token only (fp32 out, final norm) ----------------
__global__ __launch_bounds__(384) void k_lncls(const float* __restrict__ X,
                                               const float* __restrict__ w, const float* __restrict__ b,
                                               float* __restrict__ Y) {
    int bb = blockIdx.x;
    int tid = threadIdx.x;
    const float* row = X + (size_t)bb * kBAND * kD;
    float v = row[tid];
    float s1 = v, s2 = v * v;
#pragma unroll
    for (int off = 32; off; off >>= 1) { s1 += __shfl_down(s1, off, 64); s2 += __shfl_down(s2, off, 64); }
    __shared__ float r1[8], r2[8];
    int wid = tid >> 6, lane = tid & 63;
    if (lane == 0) { r1[wid] = s1; r2[wid] = s2; }
    __syncthreads();
    float sum = r1[0] + r1[1] + r1[2] + r1[3] + r1[4] + r1[5];
    float sq = r2[0] + r2[1] + r2[2] + r2[3] + r2[4] + r2[5];
    float mu = sum * (1.f / 384.f);
    float var = fmaxf(sq * (1.f / 384.f) - mu * mu, 0.f);
    Y[(size_t)bb * kD + tid] = (v - mu) * rsqrtf(var + kEPS) * w[tid] + b[tid];
}

// ---------------- MFMA flash attention: one block per (b,h) ----------------
__global__ __launch_bounds__(256) void k_attn2(const float* __restrict__ qsplit,
                                               __hip_bfloat16* __restrict__ o,
                                               const int* __restrict__ si,
                                               const int* __restrict__ keep) {
    __shared__ __align__(16) unsigned short Kb[224][72];
    __shared__ __align__(16) unsigned short Vt[64][228];
    __shared__ __align__(16) unsigned short Pb[4][16][228];
    int Nt = si[0];
    int bh = blockIdx.x;
    int b = bh / kH, h = bh - b * kH;
    int tid = threadIdx.x, w = tid >> 6, lane = tid & 63;
    int l15 = lane & 15, l4 = lane >> 4;
    int nJT = (Nt + 15) >> 4;
    int nKT = (Nt + 31) >> 5;
    int NTP = nKT << 5;

    const float* qb = qsplit + (size_t)bh * kBAND * 64;
    const float* kb = qsplit + kWQ + (size_t)bh * kBAND * 64;
    const float* vb = qsplit + 2 * kWQ + (size_t)bh * kBAND * 64;

    {
        int rr = tid >> 3;
        int c8 = (tid & 7) << 3;
        for (int r = rr; r < NTP; r += 32) {
            unsigned short ks[8], vs[8];
#pragma unroll
            for (int e = 0; e < 8; ++e) { ks[e] = 0; vs[e] = 0; }
            if (r < Nt) {
                int old = keep[r];
                const float* kr = kb + ((size_t)old << 6) + c8;
                const float* vr = vb + ((size_t)old << 6) + c8;
                float4 k0 = *(const float4*)kr, k1 = *(const float4*)(kr + 4);
                float4 vv0 = *(const float4*)vr, vv1 = *(const float4*)(vr + 4);
                ks[0] = f2bf(k0.x); ks[1] = f2bf(k0.y); ks[2] = f2bf(k0.z); ks[3] = f2bf(k0.w);
                ks[4] = f2bf(k1.x); ks[5] = f2bf(k1.y); ks[6] = f2bf(k1.z); ks[7] = f2bf(k1.w);
                vs[0] = f2bf(vv0.x); vs[1] = f2bf(vv0.y); vs[2] = f2bf(vv0.z); vs[3] = f2bf(vv0.w);
                vs[4] = f2bf(vv1.x); vs[5] = f2bf(vv1.y); vs[6] = f2bf(vv1.z); vs[7] = f2bf(vv1.w);
            }
            *(uint4*)&Kb[r][c8] = *(uint4*)ks;
#pragma unroll
            for (int e = 0; e < 8; ++e) Vt[c8 + e][r] = vs[e];
        }
    }
    __syncthreads();

    for (int strip = w; strip < nJT; strip += 4) {
        int tq = (strip << 4) + l15;
        int told = (tq < Nt) ? keep[tq] : 0;
        const float* qrow = qb + ((size_t)told << 6) + (l4 << 3);
        float4 q0 = *(const float4*)(qrow),      q1 = *(const float4*)(qrow + 4);
        float4 q2 = *(const float4*)(qrow + 32), q3 = *(const float4*)(qrow + 36);
        unsigned short qa[8], qc[8];
        qa[0] = f2bf(q0.x); qa[1] = f2bf(q0.y); qa[2] = f2bf(q0.z); qa[3] = f2bf(q0.w);
        qa[4] = f2bf(q1.x); qa[5] = f2bf(q1.y); qa[6] = f2bf(q1.z); qa[7] = f2bf(q1.w);
        qc[0] = f2bf(q2.x); qc[1] = f2bf(q2.y); qc[2] = f2bf(q2.z); qc[3] = f2bf(q2.w);
        qc[4] = f2bf(q3.x); qc[5] = f2bf(q3.y); qc[6] = f2bf(q3.z); qc[7] = f2bf(q3.w);
        short8 qf0 = *(short8*)qa;
        short8 qf1 = *(short8*)qc;

        f32x4 sv[13];
#pragma unroll
        for (int jt = 0; jt < 13; ++jt) {
            if (jt < nJT) {
                const unsigned short* kr = &Kb[(jt << 4) + l15][l4 << 3];
                short8 kf0 = *(const short8*)(kr);
                short8 kf1 = *(const short8*)(kr + 32);
                f32x4 a = {};
                a = __builtin_amdgcn_mfma_f32_16x16x32_bf16(qf0, kf0, a, 0, 0, 0);
                a = __builtin_amdgcn_mfma_f32_16x16x32_bf16(qf1, kf1, a, 0, 0, 0);
                sv[jt] = a;
            }
        }
        float mx[4] = { -INFINITY, -INFINITY, -INFINITY, -INFINITY };
#pragma unroll
        for (int jt = 0; jt < 13; ++jt) if (jt < nJT) {
            bool ok = ((jt << 4) + l15) < Nt;
#pragma unroll
            for (int r = 0; r < 4; ++r) {
                float s = ok ? sv[jt][r] * kSCALE : -INFINITY;
                sv[jt][r] = s;
                mx[r] = fmaxf(mx[r], s);
            }
        }
#pragma unroll
        for (int r = 0; r < 4; ++r) {
            mx[r] = fmaxf(mx[r], __shfl_xor(mx[r], 1, 64));
            mx[r] = fmaxf(mx[r], __shfl_xor(mx[r], 2, 64));
            mx[r] = fmaxf(mx[r], __shfl_xor(mx[r], 4, 64));
            mx[r] = fmaxf(mx[r], __shfl_xor(mx[r], 8, 64));
        }
        float sm[4] = { 0.f, 0.f, 0.f, 0.f };
#pragma unroll
        for (int jt = 0; jt < 13; ++jt) if (jt < nJT) {
#pragma unroll
            for (int r = 0; r < 4; ++r) {
                float p = expf(sv[jt][r] - mx[r]);
                sv[jt][r] = p;
                sm[r] += p;
            }
        }
#pragma unroll
        for (int r = 0; r < 4; ++r) {
            sm[r] += __shfl_xor(sm[r], 1, 64);
            sm[r] += __shfl_xor(sm[r], 2, 64);
            sm[r] += __shfl_xor(sm[r], 4, 64);
            sm[r] += __shfl_xor(sm[r], 8, 64);
            sm[r] = 1.f / sm[r];
        }
#pragma unroll
        for (int jt = 0; jt < 13; ++jt) if (jt < nJT) {
#pragma unroll
            for (int r = 0; r < 4; ++r)
                Pb[w][(l4 << 2) + r][(jt << 4) + l15] = f2bf(sv[jt][r] * sm[r]);
        }
        for (int c = (nJT << 4) + lane; c < NTP; c += 64) {
#pragma unroll
            for (int rr2 = 0; rr2 < 16; ++rr2) Pb[w][rr2][c] = 0;
        }
        asm volatile("s_waitcnt lgkmcnt(0)" ::: "memory");
        __builtin_amdgcn_sched_barrier(0);

        f32x4 oacc[4] = { {}, {}, {}, {} };
#pragma unroll
        for (int kt = 0; kt < 7; ++kt) if (kt < nKT) {
            short8 pf = *(const short8*)&Pb[w][l15][(kt << 5) + (l4 << 3)];
#pragma unroll
            for (int dt = 0; dt < 4; ++dt) {
                short8 vf = *(const short8*)&Vt[(dt << 4) + l15][(kt << 5) + (l4 << 3)];
                oacc[dt] = __builtin_amdgcn_mfma_f32_16x16x32_bf16(pf, vf, oacc[dt], 0, 0, 0);
            }
        }
#pragma unroll
        for (int dt = 0; dt < 4; ++dt) {
#pragma unroll
            for (int r = 0; r < 4; ++r) {
                int tqo = (strip << 4) + (l4 << 2) + r;
                if (tqo < Nt)
                    o[((size_t)b * kBAND + tqo) * kD + h * 64 + (dt << 4) + l15] =
                        __float2bfloat16(oacc[dt][r]);
            }
        }
    }
}

// ---------------- decision A: per-batch importance (reads split fp32 qkv) ----------------
__global__ __launch_bounds__(256) void k_decA(const float* __restrict__ qsplit, float* __restrict__ imp,
                                              float* __restrict__ sab, const int* __restrict__ si) {
    int Nt = si[0];
    if (Nt - 1 <= 16) return;
    int b = blockIdx.x;
    int tid = threadIdx.x;
    __shared__ float qs[64];
    __shared__ float red[256];
    int j = tid;
    float acc6 = 0.f;
    for (int h = 0; h < kH; ++h) {
        size_t bh = (size_t)b * kH + h;
        const float* qp = qsplit + bh * kBAND * 64;
        const float* kp = qsplit + kWQ + bh * kBAND * 64;
        const float* vp = qsplit + 2 * kWQ + bh * kBAND * 64;
        if (tid < 64) qs[tid] = qp[tid];      // q of cls (token 0)
        __syncthreads();
        float s = -INFINITY, vn = 0.f;
        if (j < Nt) {
            const float* krow = kp + ((size_t)j << 6);
            const float* vrow = vp + ((size_t)j << 6);
            float a = 0.f, v2 = 0.f;
#pragma unroll
            for (int d = 0; d < 64; d += 4) {
                float4 k4 = *(const float4*)(krow + d);
                float4 v4 = *(const float4*)(vrow + d);
                a += qs[d] * k4.x + qs[d + 1] * k4.y + qs[d + 2] * k4.z + qs[d + 3] * k4.w;
                v2 += v4.x * v4.x + v4.y * v4.y + v4.z * v4.z + v4.w * v4.w;
            }
            s = a * kSCALE;
            vn = sqrtf(v2);
        }
        red[tid] = s; __syncthreads();
        for (int st = 128; st; st >>= 1) { if (tid < st) red[tid] = fmaxf(red[tid], red[tid + st]); __syncthreads(); }
        float m = red[0]; __syncthreads();
        float e = (j < Nt) ? expf(s - m) : 0.f;
        red[tid] = e; __syncthreads();
        for (int st = 128; st; st >>= 1) { if (tid < st) red[tid] += red[tid + st]; __syncthreads(); }
        float inv = 1.f / red[0];
        acc6 += e * inv * vn;
        __syncthreads();
    }
    float v = (j < Nt) ? acc6 * (1.f / 6.f) : 0.f;
    if (j < Nt) imp[(size_t)b * kBAND + j] = v;
    red[tid] = v; __syncthreads();
    for (int st = 128; st; st >>= 1) { if (tid < st) red[tid] += red[tid + st]; __syncthreads(); }
    if (tid == 0) {
        float sa = red[0];
        sab[2 * b] = sa;
        sab[2 * b + 1] = sa - v;   // tid==0 holds token-0 imp
    }
}

// ---------------- decision B: mass/ratio, rank-based top-k, keep, commit Nt ----------------
__global__ __launch_bounds__(256) void k_decB(int* si, float* sf, const float* __restrict__ imp,
                                              const float* __restrict__ sab, int* keep) {
    int Nt = si[0];
    int tid = threadIdx.x;
    if (Nt - 1 <= 16) {
        for (int jj = tid; jj < Nt; jj += 256) keep[jj] = jj;
        return;
    }
    int N = Nt - 1;
    __shared__ float red[256];
    __shared__ float sc[200];
    __shared__ int flag[200];
    float v = (tid < kB) ? sab[2 * tid + 1] / (sab[2 * tid] + kEPS) : 0.f;
    red[tid] = v; __syncthreads();
    for (int st = 128; st; st >>= 1) { if (tid < st) red[tid] += red[tid + st]; __syncthreads(); }
    float mass = red[0] * (1.f / 64.f);
    float prev = sf[0];
    float ratio = 0.5f * mass / (prev + kEPS);
    ratio = fminf(fmaxf(ratio, 0.f), 1.f);
    int N_next = (int)((double)N * (double)ratio);
    if (N_next < 16) N_next = 16;
    if (tid == 0) sf[0] = mass;
    __syncthreads();
    if (N_next >= N) {
        for (int jj = tid; jj < Nt; jj += 256) keep[jj] = jj;
        return;
    }
    if (tid < N) {
        float s = 0.f;
        for (int b = 0; b < kB; ++b) s += imp[(size_t)b * kBAND + tid + 1];
        sc[tid] = s;
    }
    __syncthreads();
    if (tid < N) {
        float s = sc[tid];
        int rank = 0;
        for (int i = 0; i < N; ++i) {
            float oth = sc[i];
            rank += (oth > s) || (oth == s && i < tid);
        }
        flag[tid] = (rank < N_next) ? 1 : 0;
    }
    __syncthreads();
    if (tid == 0) {
        keep[0] = 0;
        int pos = 1;
        for (int jj = 0; jj < N; ++jj) if (flag[jj]) keep[pos++] = jj + 1;
        si[0] = N_next + 1;
    }
}

// ---------------- head ----------------
__global__ __launch_bounds__(256) void k_head(const float* __restrict__ xn, const float* __restrict__ hw,
                                              const float* __restrict__ hb, float* __restrict__ out) {
    int b = blockIdx.x >> 2;
    int n = ((blockIdx.x & 3) << 8) + threadIdx.x;
    __shared__ float xs[384];
    for (int i = threadIdx.x; i < 384; i += 256) xs[i] = xn[(size_t)b * kD + i];
    __syncthreads();
    if (n >= kNCLS) return;
    const float* wrow = hw + (size_t)n * kD;
    float acc = 0.f;
#pragma unroll 8
    for (int d = 0; d < kD; d += 4) {
        float4 w4 = *(const float4*)(wrow + d);
        acc += xs[d] * w4.x + xs[d + 1] * w4.y + xs[d + 2] * w4.z + xs[d + 3] * w4.w;
    }
    out[(size_t)b * kNCLS + n] = acc + hb[n];
}

// ---------------- host launch ----------------
extern "C" void kernel_launch(void* const* d_in, const int* in_sizes, int n_in,
                              void* d_out, int out_size, void* d_ws, size_t ws_size,
                              hipStream_t stream) {
    const float* x       = (const float*)d_in[0];
    const float* patch_w = (const float*)d_in[1];
    const float* patch_b = (const float*)d_in[2];
    const float* cls_tok = (const float*)d_in[3];
    const float* pos     = (const float*)d_in[4];
    const float* ln1w    = (const float*)d_in[5];
    const float* ln1b    = (const float*)d_in[6];
    const float* qkvw    = (const float*)d_in[7];
    const float* qkvb    = (const float*)d_in[8];
    const float* projw   = (const float*)d_in[9];
    const float* projb   = (const float*)d_in[10];
    const float* ln2w    = (const float*)d_in[11];
    const float* ln2b    = (const float*)d_in[12];
    const float* fc1w    = (const float*)d_in[13];
    const float* fc1b    = (const float*)d_in[14];
    const float* fc2w    = (const float*)d_in[15];
    const float* fc2b    = (const float*)d_in[16];
    const float* normw   = (const float*)d_in[17];
    const float* normb   = (const float*)d_in[18];
    const float* headw   = (const float*)d_in[19];
    const float* headb   = (const float*)d_in[20];
    float* out = (float*)d_out;

    char* ws = (char*)d_ws;
    const size_t MB = 1024ull * 1024ull;
    int*   si   = (int*)ws;
    float* sf   = (float*)(ws + 64);
    int*   keep = (int*)(ws + 256);
    float* imp  = (float*)(ws + 4096);
    float* sab  = (float*)(ws + 128 * 1024);
    float* xnm  = (float*)(ws + 256 * 1024);
    float* xtA  = (float*)(ws + 1 * MB);                      // 19.4 MB
    float* xtB  = (float*)(ws + 21 * MB);                     // 19.4 MB
    __hip_bfloat16* xn   = (__hip_bfloat16*)(ws + 41 * MB);   // 9.7 MB; aliased: attn out
    __hip_bfloat16* Aim    = (__hip_bfloat16*)(ws + 51 * MB);
    float*          xp     = (float*)(ws + 71 * MB);
    float*          qsplit = (float*)(ws + 51 * MB);
    __hip_bfloat16* hbuf   = (__hip_bfloat16*)(ws + 51 * MB);
    __hip_bfloat16* wpat = (__hip_bfloat16*)(ws + 110 * MB);
    __hip_bfloat16* wqkv = (__hip_bfloat16*)(ws + 111 * MB);
    __hip_bfloat16* wprj = (__hip_bfloat16*)(ws + 122 * MB);
    __hip_bfloat16* wfc1 = (__hip_bfloat16*)(ws + 126 * MB);
    __hip_bfloat16* wfc2 = (__hip_bfloat16*)(ws + 141 * MB);
    __hip_bfloat16* obuf = xn;

    k_init<<<1, 64, 0, stream>>>(si, sf);
    k_cvtall<<<2048, 256, 0, stream>>>(patch_w, qkvw, projw, fc1w, fc2w,
                                       wpat, wqkv, wprj, wfc1, wfc2);

    k_im2col<<<kB * kNP, 256, 0, stream>>>(x, Aim);
    k_mgemm<0, 0, 0><<<8 * 6 * 25, 256, 0, stream>>>(
        (const unsigned short*)Aim, 768, (const unsigned short*)wpat, 768,
        (const float*)nullptr, xp, kD, (const float*)nullptr, (const int*)nullptr,
        196, 6, 196, (const int*)nullptr, 196);
    k_assemble<<<kB * kBAND, 384, 0, stream>>>(xp, patch_b, cls_tok, pos, xtA);

    float* cur = xtA; float* oth = xtB;
    for (int l = 0; l < kL; ++l) {
        const float* l1w = ln1w + l * kD;  const float* l1b = ln1b + l * kD;
        const __hip_bfloat16* qw = wqkv + (size_t)l * 1152 * kD;
        const float* qb = qkvb + l * 1152;
        const __hip_bfloat16* pw = wprj + (size_t)l * kD * kD;
        const float* pb = projb + l * kD;
        const float* l2w = ln2w + l * kD;  const float* l2b = ln2b + l * kD;
        const __hip_bfloat16* f1w = wfc1 + (size_t)l * 1536 * kD;
        const float* f1b = fc1b + l * 1536;
        const __hip_bfloat16* f2w = wfc2 + (size_t)l * kD * 1536;
        const float* f2b = fc2b + l * kD;

        // LN + qkv GEMM on OLD token set -> split fp32 q/k/v
        k_ln<<<kB * kBAND, 384, 0, stream>>>(cur, xn, l1w, l1b, si);
        k_mgemm<0, 0, 1><<<8 * 18 * 25, 256, 0, stream>>>(
            (const unsigned short*)xn, kD, (const unsigned short*)qw, kD,
            qb, qsplit, 1152, (const float*)nullptr, (const int*)nullptr,
            197, 18, kBAND, si, 0);
        // decision (device-gated); decB commits new Nt into si[0]
        k_decA<<<kB, 256, 0, stream>>>(qsplit, imp, sab, si);
        k_decB<<<1, 256, 0, stream>>>(si, sf, imp, sab, keep);
        // attention on pruned tokens (reads q/k/v via keep)
        k_attn2<<<kB * kH, 256, 0, stream>>>(qsplit, obuf, si, keep);
        // proj + pruned-residual (gather fused via keep), write to other buffer
        k_mgemm<0, 0, 0><<<8 * 6 * 25, 256, 0, stream>>>(
            (const unsigned short*)obuf, kD, (const unsigned short*)pw, kD,
            pb, oth, kD, cur, keep, 197, 6, kBAND, si, 0);
        { float* tmp = cur; cur = oth; oth = tmp; }
        // MLP
        k_ln<<<kB * kBAND, 384, 0, stream>>>(cur, xn, l2w, l2b, si);
        k_mgemm<1, 1, 0><<<8 * 24 * 25, 256, 0, stream>>>(
            (const unsigned short*)xn, kD, (const unsigned short*)f1w, kD,
            f1b, hbuf, 1536, (const float*)nullptr, (const int*)nullptr,
            197, 24, kBAND, si, 0);
        k_mgemm<0, 0, 0><<<8 * 6 * 25, 256, 0, stream>>>(
            (const unsigned short*)hbuf, 1536, (const unsigned short*)f2w, 1536,
            f2b, cur, kD, cur, (const int*)nullptr, 197, 6, kBAND, si, 0);
    }

    k_lncls<<<kB, 384, 0, stream>>>(cur, normw, normb, xnm);
    k_head<<<kB * 4, 256, 0, stream>>>(xnm, headw, headb, out);
}